// Round 10
// baseline (1229.847 us; speedup 1.0000x reference)
//
#include <hip/hip_runtime.h>
#include <hip/hip_bf16.h>
#include <stdint.h>

// Problem constants
#define SEQ   8192
#define HDIM  3072
#define NWIN  19
#define WINL  512
#define STR   448
#define NHEAD 12
#define DHEAD 256
#define QKVN  9216
#define ATTN_SCALE 0.0625f

typedef unsigned short u16;
typedef __bf16 bf16x8 __attribute__((ext_vector_type(8)));
typedef float  f32x4  __attribute__((ext_vector_type(4)));
typedef unsigned short us8 __attribute__((ext_vector_type(8)));

__device__ __forceinline__ u16 f2b(float x) {
  return __builtin_bit_cast(u16, __float2bfloat16(x));
}
__device__ __forceinline__ float b2f(u16 u) {
  return __builtin_bit_cast(float, (unsigned int)(u) << 16);
}
__device__ __forceinline__ void gload_lds16(const void* g, void* l) {
  __builtin_amdgcn_global_load_lds(
      (const __attribute__((address_space(1))) void*)g,
      (__attribute__((address_space(3))) void*)l, 16, 0, 0);
}

// ---------------- elementwise converts ----------------
__global__ __launch_bounds__(256) void cvt_f32_bf16(const float* __restrict__ src,
                                                    u16* __restrict__ dst, int n8) {
  int i = blockIdx.x * 256 + threadIdx.x;
  if (i >= n8) return;
  const float4* s4 = (const float4*)src;
  float4 a = s4[2 * i], b = s4[2 * i + 1];
  us8 o;
  o[0] = f2b(a.x); o[1] = f2b(a.y); o[2] = f2b(a.z); o[3] = f2b(a.w);
  o[4] = f2b(b.x); o[5] = f2b(b.y); o[6] = f2b(b.z); o[7] = f2b(b.w);
  *((us8*)dst + i) = o;
}

__global__ __launch_bounds__(256) void biascat(const float* __restrict__ bq,
                                               const float* __restrict__ bk,
                                               const float* __restrict__ bv,
                                               float* __restrict__ dst) {
  int i = blockIdx.x * 256 + threadIdx.x;
  if (i >= QKVN) return;
  dst[i] = (i < HDIM) ? bq[i] : ((i < 2 * HDIM) ? bk[i - HDIM] : bv[i - 2 * HDIM]);
}

// ---------------- 256x256 8-phase GEMM (R4-exact): C = A * B^T (+bias) ----------------
// A[M][K] bf16 row-major, B[N][K] bf16 row-major. K-tile BK=64.
// 8 waves (2Mx4N). INTERLEAVED ownership (correctness-critical):
//   C rows  mi*32 + wm*16 + {0..15}, mi=0..7  (mi0-3 in A-lo half, mi4-7 A-hi)
//   C cols  ni*64 + wn*16 + {0..15}, ni=0..3  (ni0-1 in B-lo half, ni2-3 B-hi)
// => P0 touches ONLY lo halves for every wave; half-readiness matches vmcnt ledger.
// LDS: [2 dbuf][2 half][128][64] per operand = 128 KiB. 16B-chunk swizzle:
// phys_chunk = logical ^ (row&7), both sides.
// If BF16OUT and vtOut != nullptr, columns c >= 2*HDIM also write the
// transposed V panel: Vt[(c-6144)][r0..r0+3] (one 8B store per (mi,ni)).
template <bool BF16OUT>
__global__ __launch_bounds__(512, 2) void gemm256(const u16* __restrict__ A,
                                                  const u16* __restrict__ B,
                                                  const float* __restrict__ bias,
                                                  float* __restrict__ outF,
                                                  u16* __restrict__ outB,
                                                  u16* __restrict__ vtOut,
                                                  int N, int K) {
  __shared__ __align__(16) u16 As[2][2][128][64];
  __shared__ __align__(16) u16 Bs[2][2][128][64];
  const int tid = threadIdx.x;
  const int w = tid >> 6, l = tid & 63;
  const int wm = w >> 2, wn = w & 3;
  const int fr = l & 15, g = l >> 4;
  // XCD-band mapping (hardware round-robin bid->XCD = bid%8); nbm = 32 = 8x4.
  const int xcd = blockIdx.x & 7, loc = blockIdx.x >> 3;
  const int bn = loc >> 2, bm = xcd * 4 + (loc & 3);

  // Staging: thread t writes half bytes t*16 and 8192+t*16
  //  -> rows t>>3 and 64+(t>>3), phys chunk t&7; source chunk inverse-swizzled.
  const int srow = tid >> 3;
  const int lc = (tid & 7) ^ ((tid >> 3) & 7);
  const u16* sA0 = A + (size_t)(bm * 256 + srow) * K + lc * 8;
  const u16* sA1 = sA0 + (size_t)64 * K;
  const u16* sB0 = B + (size_t)(bn * 256 + srow) * K + lc * 8;
  const u16* sB1 = sB0 + (size_t)64 * K;
  const size_t hiK = (size_t)128 * K;
  const int t16 = tid * 16;
  char* Aw = (char*)As;
  char* Bw = (char*)Bs;

  // Fragment read offsets (bytes within a [128][64] half):
  //  A row = mi*32 + wm*16 + fr ; B row = (ni&1)*64 + wn*16 + fr
  //  chunk = (kk*4+g) ^ (row&7); row&7 == fr&7 for all fragments.
  int rbA[4], rbB[2], ck[2];
#pragma unroll
  for (int i = 0; i < 4; ++i) rbA[i] = (i * 32 + wm * 16 + fr) * 128;
  rbB[0] = (wn * 16 + fr) * 128;
  rbB[1] = (64 + wn * 16 + fr) * 128;
  ck[0] = ((g) ^ (fr & 7)) * 16;
  ck[1] = ((4 + g) ^ (fr & 7)) * 16;

  f32x4 acc[8][4];
#pragma unroll
  for (int i = 0; i < 8; ++i)
#pragma unroll
    for (int j = 0; j < 4; ++j) acc[i][j] = (f32x4){0.f, 0.f, 0.f, 0.f};

  // prologue: stage tile0 (Alo,Blo,Bhi,Ahi) into parity 0
  gload_lds16(sA0, Aw + t16); gload_lds16(sA1, Aw + 8192 + t16);
  gload_lds16(sB0, Bw + t16); gload_lds16(sB1, Bw + 8192 + t16);
  gload_lds16(sB0 + hiK, Bw + 16384 + t16); gload_lds16(sB1 + hiK, Bw + 16384 + 8192 + t16);
  gload_lds16(sA0 + hiK, Aw + 16384 + t16); gload_lds16(sA1 + hiK, Aw + 16384 + 8192 + t16);
  sA0 += 64; sA1 += 64; sB0 += 64; sB1 += 64;  // -> tile 1
  asm volatile("s_waitcnt vmcnt(4)" ::: "memory");
  __builtin_amdgcn_s_barrier();
  __builtin_amdgcn_sched_barrier(0);

  const int NT = K >> 6;
  for (int T = 0; T < NT; ++T) {
    const int cur = T & 1, pp = (T + 1) & 1;
    const bool ds = (T + 1 < NT);
    const bool last = (T == NT - 1);
    const char* ah = (const char*)As + cur * 32768;
    const char* bh = (const char*)Bs + cur * 32768;
    char* apw = Aw + pp * 32768;
    char* bpw = Bw + pp * 32768;
    bf16x8 af[4][2], bf[4][2];

    // ---------------- P0 ----------------
#pragma unroll
    for (int mi = 0; mi < 4; ++mi)
#pragma unroll
      for (int kk = 0; kk < 2; ++kk)
        af[mi][kk] = *(const bf16x8*)(ah + rbA[mi] + ck[kk]);
#pragma unroll
    for (int ni = 0; ni < 2; ++ni)
#pragma unroll
      for (int kk = 0; kk < 2; ++kk)
        bf[ni][kk] = *(const bf16x8*)(bh + rbB[ni] + ck[kk]);
    if (ds) { gload_lds16(sA0, apw + t16); gload_lds16(sA1, apw + 8192 + t16); }
    __builtin_amdgcn_s_barrier();
    asm volatile("s_waitcnt lgkmcnt(0)" ::: "memory");
    __builtin_amdgcn_sched_barrier(0);
    __builtin_amdgcn_s_setprio(1);
#pragma unroll
    for (int kk = 0; kk < 2; ++kk)
#pragma unroll
      for (int mi = 0; mi < 4; ++mi)
#pragma unroll
        for (int ni = 0; ni < 2; ++ni)
          acc[mi][ni] = __builtin_amdgcn_mfma_f32_16x16x32_bf16(af[mi][kk], bf[ni][kk], acc[mi][ni], 0, 0, 0);
    __builtin_amdgcn_s_setprio(0);
    if (last) asm volatile("s_waitcnt vmcnt(2)" ::: "memory");
    else      asm volatile("s_waitcnt vmcnt(4)" ::: "memory");
    __builtin_amdgcn_s_barrier();

    // ---------------- P1 ----------------
#pragma unroll
    for (int ni = 2; ni < 4; ++ni)
#pragma unroll
      for (int kk = 0; kk < 2; ++kk)
        bf[ni][kk] = *(const bf16x8*)(bh + 16384 + rbB[ni - 2] + ck[kk]);
    if (ds) { gload_lds16(sB0, bpw + t16); gload_lds16(sB1, bpw + 8192 + t16); }
    __builtin_amdgcn_s_barrier();
    asm volatile("s_waitcnt lgkmcnt(0)" ::: "memory");
    __builtin_amdgcn_sched_barrier(0);
    __builtin_amdgcn_s_setprio(1);
#pragma unroll
    for (int kk = 0; kk < 2; ++kk)
#pragma unroll
      for (int mi = 0; mi < 4; ++mi)
#pragma unroll
        for (int ni = 2; ni < 4; ++ni)
          acc[mi][ni] = __builtin_amdgcn_mfma_f32_16x16x32_bf16(af[mi][kk], bf[ni][kk], acc[mi][ni], 0, 0, 0);
    __builtin_amdgcn_s_setprio(0);
    if (last) asm volatile("s_waitcnt vmcnt(0)" ::: "memory");
    else      asm volatile("s_waitcnt vmcnt(4)" ::: "memory");
    __builtin_amdgcn_s_barrier();

    // ---------------- P2 ----------------
#pragma unroll
    for (int mi = 0; mi < 4; ++mi)
#pragma unroll
      for (int kk = 0; kk < 2; ++kk)
        af[mi][kk] = *(const bf16x8*)(ah + 16384 + rbA[mi] + ck[kk]);
    if (ds) { gload_lds16(sB0 + hiK, bpw + 16384 + t16); gload_lds16(sB1 + hiK, bpw + 16384 + 8192 + t16); }
    __builtin_amdgcn_s_barrier();
    asm volatile("s_waitcnt lgkmcnt(0)" ::: "memory");
    __builtin_amdgcn_sched_barrier(0);
    __builtin_amdgcn_s_setprio(1);
#pragma unroll
    for (int kk = 0; kk < 2; ++kk)
#pragma unroll
      for (int mi = 0; mi < 4; ++mi)
#pragma unroll
        for (int ni = 0; ni < 2; ++ni)
          acc[mi + 4][ni] = __builtin_amdgcn_mfma_f32_16x16x32_bf16(af[mi][kk], bf[ni][kk], acc[mi + 4][ni], 0, 0, 0);
    __builtin_amdgcn_s_setprio(0);
    __builtin_amdgcn_s_barrier();

    // ---------------- P3 ----------------
    if (ds) { gload_lds16(sA0 + hiK, apw + 16384 + t16); gload_lds16(sA1 + hiK, apw + 16384 + 8192 + t16); }
    __builtin_amdgcn_s_barrier();
    __builtin_amdgcn_s_setprio(1);
#pragma unroll
    for (int kk = 0; kk < 2; ++kk)
#pragma unroll
      for (int mi = 0; mi < 4; ++mi)
#pragma unroll
        for (int ni = 2; ni < 4; ++ni)
          acc[mi + 4][ni] = __builtin_amdgcn_mfma_f32_16x16x32_bf16(af[mi][kk], bf[ni][kk], acc[mi + 4][ni], 0, 0, 0);
    __builtin_amdgcn_s_setprio(0);
    if (!last) asm volatile("s_waitcnt vmcnt(4)" ::: "memory");
    __builtin_amdgcn_s_barrier();
    if (ds) { sA0 += 64; sA1 += 64; sB0 += 64; sB1 += 64; }
    __builtin_amdgcn_sched_barrier(0);
  }

  // epilogue (+ optional fused V-transpose write)
#pragma unroll
  for (int ni = 0; ni < 4; ++ni) {
    const int c = bn * 256 + ni * 64 + wn * 16 + fr;
    const float bvv = bias ? bias[c] : 0.0f;
    const bool wv = BF16OUT && (vtOut != nullptr) && (c >= 2 * HDIM);
#pragma unroll
    for (int mi = 0; mi < 8; ++mi) {
      const int r0 = bm * 256 + mi * 32 + wm * 16 + g * 4;
      u16 t4[4];
#pragma unroll
      for (int jj = 0; jj < 4; ++jj) {
        float v = acc[mi][ni][jj] + bvv;
        if (BF16OUT) { u16 b_ = f2b(v); outB[(size_t)(r0 + jj) * N + c] = b_; t4[jj] = b_; }
        else         outF[(size_t)(r0 + jj) * N + c] = v;
      }
      if (wv) *(uint2*)(vtOut + (size_t)(c - 2 * HDIM) * SEQ + r0) = *(const uint2*)t4;
    }
  }
}

// ---------------- windowed flash attention: direct-global K/V, barrier-free ----------------
// grid (8 qb, 12 h, 19 win), 4 independent waves; 16 q-rows/wave; 8 kv-chunks of 64.
// K/V fragments read straight from L2 (K,V slices are 256KB per (h,n), shared by
// 8 qb-blocks -> L2-hot; staging them in LDS was pure overhead + barriers).
// LDS: only Ps[4][16][64] (wave-private P transpose buffer, R1-proven swizzle).
// T13 defer-rescale: skip ctx rescale unless any lane's score exceeds mrow+8
// (per-lane check, no max-reduction on the common path). P bounded by e^8 — fine
// in bf16/f32. Window-validity is 64-aligned (448%64==0) so masked chunks are
// all-invalid: P==0 exactly, V col clamped to SEQ-64 keeps reads finite.
__global__ __launch_bounds__(256, 3) void attn_kernel(const u16* __restrict__ QKV,
                                                      const u16* __restrict__ Vt,
                                                      u16* __restrict__ ctxw) {
  __shared__ __align__(16) u16 Ps[4][16 * 64];  // 8 KiB
  const int qb = blockIdx.x, h = blockIdx.y, n = blockIdx.z;
  const int tid = threadIdx.x, w = tid >> 6, l = tid & 63;
  const int g = l >> 4, fr = l & 15;
  const int s0 = n * STR;

  // Q fragments (16 rows per wave) straight from global
  bf16x8 qf[8];
  {
    int sq = s0 + qb * 64 + w * 16 + fr;
    if (sq > SEQ - 1) sq = SEQ - 1;
    const u16* qbase = QKV + (size_t)sq * QKVN + h * DHEAD + g * 8;
#pragma unroll
    for (int dc = 0; dc < 8; ++dc) qf[dc] = *(const bf16x8*)(qbase + dc * 32);
  }
  f32x4 ctx[16];
#pragma unroll
  for (int dn = 0; dn < 16; ++dn) ctx[dn] = (f32x4){0.f, 0.f, 0.f, 0.f};
  float mrow[4] = {-3e38f, -3e38f, -3e38f, -3e38f};
  float lrow[4] = {0.f, 0.f, 0.f, 0.f};

  const u16* kbase = QKV + HDIM + h * DHEAD;             // + row*QKVN + chunk
  const u16* vbase = Vt + (size_t)(h * DHEAD) * SEQ;     // + d*SEQ + col
  char* pw = (char*)&Ps[w][0];

  for (int kt = 0; kt < 8; ++kt) {
    const int sb = s0 + kt * 64;
    const int sbc = (sb > SEQ - 64) ? (SEQ - 64) : sb;   // V col clamp (finite reads)

    // ---- S = Q K^T, K fragments direct from global (L2) ----
    f32x4 sacc[4];
#pragma unroll
    for (int kn = 0; kn < 4; ++kn) sacc[kn] = (f32x4){0.f, 0.f, 0.f, 0.f};
#pragma unroll
    for (int kn = 0; kn < 4; ++kn) {
      int sk = sb + kn * 16 + fr;
      if (sk > SEQ - 1) sk = SEQ - 1;
      const u16* kr = kbase + (size_t)sk * QKVN;
#pragma unroll
      for (int dc = 0; dc < 8; ++dc) {
        bf16x8 kf = *(const bf16x8*)(kr + (dc * 4 + g) * 8);
        sacc[kn] = __builtin_amdgcn_mfma_f32_16x16x32_bf16(qf[dc], kf, sacc[kn], 0, 0, 0);
      }
    }
    // ---- scale + validity mask; per-lane defer-rescale check (T13) ----
    bool ok = true;
#pragma unroll
    for (int kn = 0; kn < 4; ++kn) {
      const bool valid = (sb + kn * 16 + fr) < SEQ;
#pragma unroll
      for (int r = 0; r < 4; ++r) {
        float v = valid ? sacc[kn][r] * ATTN_SCALE : -1e9f;
        sacc[kn][r] = v;
        ok = ok && (v <= mrow[r] + 8.0f);
      }
    }
    if (!__all(ok)) {
      // rare path: full max-reduce + rescale
      float mt[4];
#pragma unroll
      for (int kn = 0; kn < 4; ++kn)
#pragma unroll
        for (int r = 0; r < 4; ++r)
          mt[r] = (kn == 0) ? sacc[0][r] : fmaxf(mt[r], sacc[kn][r]);
#pragma unroll
      for (int r = 0; r < 4; ++r) {
#pragma unroll
        for (int off = 1; off < 16; off <<= 1)
          mt[r] = fmaxf(mt[r], __shfl_xor(mt[r], off, 64));
        float mnew = fmaxf(mrow[r], mt[r]);
        float corr = __expf(mrow[r] - mnew);
        mrow[r] = mnew;
        lrow[r] *= corr;
#pragma unroll
        for (int dn = 0; dn < 16; ++dn) ctx[dn][r] *= corr;
      }
    }
    // ---- P = exp(S - mrow); Ps write (R1-proven swizzle); psum reduce ----
    float psum[4] = {0.f, 0.f, 0.f, 0.f};
#pragma unroll
    for (int kn = 0; kn < 4; ++kn) {
#pragma unroll
      for (int r = 0; r < 4; ++r) {
        float p = __expf(sacc[kn][r] - mrow[r]);
        psum[r] += p;
        const int q = g * 4 + r;
        *(u16*)(pw + q * 128 + ((2 * (kn * 16 + fr)) ^ ((q & 7) << 4))) = f2b(p);
      }
    }
#pragma unroll
    for (int r = 0; r < 4; ++r) {
#pragma unroll
      for (int off = 1; off < 16; off <<= 1)
        psum[r] += __shfl_xor(psum[r], off, 64);
      lrow[r] += psum[r];
    }
    // same-wave ds_write -> ds_read ordering fence (rule #18)
    asm volatile("s_waitcnt lgkmcnt(0)" ::: "memory");
    __builtin_amdgcn_sched_barrier(0);

    // ---- ctx += P * V, V fragments direct from global (L2) ----
    bf16x8 pf[2];
#pragma unroll
    for (int kc = 0; kc < 2; ++kc)
      pf[kc] = *(const bf16x8*)(pw + fr * 128 + ((kc * 64 + g * 16) ^ ((fr & 7) << 4)));
#pragma unroll
    for (int dn = 0; dn < 16; ++dn) {
      const u16* vr = vbase + (size_t)(dn * 16 + fr) * SEQ + sbc;
#pragma unroll
      for (int kc = 0; kc < 2; ++kc) {
        bf16x8 vf = *(const bf16x8*)(vr + (kc * 4 + g) * 8);
        ctx[dn] = __builtin_amdgcn_mfma_f32_16x16x32_bf16(pf[kc], vf, ctx[dn], 0, 0, 0);
      }
    }
  }
  // ---- epilogue: normalize and store ctx ----
  float inv[4];
#pragma unroll
  for (int r = 0; r < 4; ++r) inv[r] = 1.0f / lrow[r];
  const int qrow0 = qb * 64 + w * 16 + g * 4;
#pragma unroll
  for (int dn = 0; dn < 16; ++dn) {
#pragma unroll
    for (int r = 0; r < 4; ++r) {
      ctxw[(size_t)(n * WINL + qrow0 + r) * HDIM + h * DHEAD + dn * 16 + fr] =
          f2b(ctx[dn][r] * inv[r]);
    }
  }
}

// ---------------- overlap-average combine: ctx_avg[8192][3072] ----------------
__global__ __launch_bounds__(256) void combine_kernel(const u16* __restrict__ ctxw,
                                                      u16* __restrict__ ctx_avg) {
  int idx = blockIdx.x * 256 + threadIdx.x;
  if (idx >= SEQ * (HDIM / 8)) return;
  const int s = idx / (HDIM / 8);
  const int cc = (idx % (HDIM / 8)) * 8;
  const int w1 = s / STR;          // <= 18
  const int off1 = s - w1 * STR;   // 0..447
  us8 a = *(const us8*)(ctxw + (size_t)(w1 * WINL + off1) * HDIM + cc);
  if (w1 >= 1 && off1 < (WINL - STR)) {
    us8 b = *(const us8*)(ctxw + (size_t)((w1 - 1) * WINL + off1 + STR) * HDIM + cc);
#pragma unroll
    for (int j = 0; j < 8; ++j) a[j] = f2b(0.5f * (b2f(a[j]) + b2f(b[j])));
  }
  *(us8*)(ctx_avg + (size_t)s * HDIM + cc) = a;
}

__global__ void ws_marker(float* out, float v) { out[0] = v; }

// ---------------- launch ----------------
extern "C" void kernel_launch(void* const* d_in, const int* in_sizes, int n_in,
                              void* d_out, int out_size, void* d_ws, size_t ws_size,
                              hipStream_t stream) {
  const float* X  = (const float*)d_in[0];
  const float* Wq = (const float*)d_in[1];
  const float* bq = (const float*)d_in[2];
  const float* Wk = (const float*)d_in[3];
  const float* bk = (const float*)d_in[4];
  const float* Wv = (const float*)d_in[5];
  const float* bv = (const float*)d_in[6];
  const float* Wo = (const float*)d_in[7];
  const float* bo = (const float*)d_in[8];
  float* out = (float*)d_out;

  // workspace layout (bytes)
  const size_t OFF_XB   = 0;                          // 8192*3072*2   = 50331648
  const size_t OFF_WQKV = 50331648;                   // 9216*3072*2   = 56623104
  const size_t OFF_WO   = 106954752;                  // 3072*3072*2   = 18874368
  const size_t OFF_QKV  = 125829120;                  // 8192*9216*2   = 150994944
  const size_t OFF_VT   = 276824064;                  // 3072*8192*2   = 50331648
  const size_t OFF_BIAS = 327155712;                  // 9216*4        = 36864
  const size_t WS_NEED  = 327192576;
  if (ws_size < WS_NEED) {
    hipMemsetAsync(d_out, 0, (size_t)out_size * 4, stream);
    ws_marker<<<1, 1, 0, stream>>>(out, (float)(ws_size / 1048576));
    return;
  }
  char* ws = (char*)d_ws;
  u16* Xb      = (u16*)(ws + OFF_XB);
  u16* Wqkvb   = (u16*)(ws + OFF_WQKV);
  u16* Wob     = (u16*)(ws + OFF_WO);
  u16* QKV     = (u16*)(ws + OFF_QKV);
  u16* Vt      = (u16*)(ws + OFF_VT);
  float* biasQ = (float*)(ws + OFF_BIAS);
  u16* ctxw    = (u16*)d_out;  // 59.8MB scratch inside the 100.7MB output buffer
  u16* ctx_avg = Xb;           // alias: Xb dead after QKV GEMM

  cvt_f32_bf16<<<12288, 256, 0, stream>>>(X, Xb, SEQ * HDIM / 8);
  cvt_f32_bf16<<<4608, 256, 0, stream>>>(Wq, Wqkvb, HDIM * HDIM / 8);
  cvt_f32_bf16<<<4608, 256, 0, stream>>>(Wk, Wqkvb + (size_t)HDIM * HDIM, HDIM * HDIM / 8);
  cvt_f32_bf16<<<4608, 256, 0, stream>>>(Wv, Wqkvb + (size_t)2 * HDIM * HDIM, HDIM * HDIM / 8);
  cvt_f32_bf16<<<4608, 256, 0, stream>>>(Wo, Wob, HDIM * HDIM / 8);
  biascat<<<36, 256, 0, stream>>>(bq, bk, bv, biasQ);

  gemm256<true><<<dim3((SEQ / 256) * (QKVN / 256)), 512, 0, stream>>>(
      Xb, Wqkvb, biasQ, nullptr, QKV, Vt, QKVN, HDIM);

  attn_kernel<<<dim3(8, NHEAD, NWIN), 256, 0, stream>>>(QKV, Vt, ctxw);

  combine_kernel<<<12288, 256, 0, stream>>>(ctxw, ctx_avg);

  gemm256<false><<<dim3((SEQ / 256) * (HDIM / 256)), 512, 0, stream>>>(
      ctx_avg, Wob, bo, out, nullptr, nullptr, HDIM, HDIM);
}

// Round 11
// 1044.446 us; speedup vs baseline: 1.1775x; 1.1775x over previous
//
#include <hip/hip_runtime.h>
#include <hip/hip_bf16.h>
#include <stdint.h>

// Problem constants
#define SEQ   8192
#define HDIM  3072
#define NWIN  19
#define WINL  512
#define STR   448
#define NHEAD 12
#define DHEAD 256
#define QKVN  9216
#define ATTN_SCALE 0.0625f

typedef unsigned short u16;
typedef __bf16 bf16x8 __attribute__((ext_vector_type(8)));
typedef float  f32x4  __attribute__((ext_vector_type(4)));
typedef unsigned short us8 __attribute__((ext_vector_type(8)));

__device__ __forceinline__ u16 f2b(float x) {
  return __builtin_bit_cast(u16, __float2bfloat16(x));
}
__device__ __forceinline__ float b2f(u16 u) {
  return __builtin_bit_cast(float, (unsigned int)(u) << 16);
}
__device__ __forceinline__ void gload_lds16(const void* g, void* l) {
  __builtin_amdgcn_global_load_lds(
      (const __attribute__((address_space(1))) void*)g,
      (__attribute__((address_space(3))) void*)l, 16, 0, 0);
}

// ---------------- elementwise converts ----------------
__global__ __launch_bounds__(256) void cvt_f32_bf16(const float* __restrict__ src,
                                                    u16* __restrict__ dst, int n8) {
  int i = blockIdx.x * 256 + threadIdx.x;
  if (i >= n8) return;
  const float4* s4 = (const float4*)src;
  float4 a = s4[2 * i], b = s4[2 * i + 1];
  us8 o;
  o[0] = f2b(a.x); o[1] = f2b(a.y); o[2] = f2b(a.z); o[3] = f2b(a.w);
  o[4] = f2b(b.x); o[5] = f2b(b.y); o[6] = f2b(b.z); o[7] = f2b(b.w);
  *((us8*)dst + i) = o;
}

__global__ __launch_bounds__(256) void biascat(const float* __restrict__ bq,
                                               const float* __restrict__ bk,
                                               const float* __restrict__ bv,
                                               float* __restrict__ dst) {
  int i = blockIdx.x * 256 + threadIdx.x;
  if (i >= QKVN) return;
  dst[i] = (i < HDIM) ? bq[i] : ((i < 2 * HDIM) ? bk[i - HDIM] : bv[i - 2 * HDIM]);
}

// ---------------- 256x256 8-phase GEMM (R4-exact): C = A * B^T (+bias) ----------------
// A[M][K] bf16 row-major, B[N][K] bf16 row-major. K-tile BK=64.
// 8 waves (2Mx4N). INTERLEAVED ownership (correctness-critical):
//   C rows  mi*32 + wm*16 + {0..15}, mi=0..7  (mi0-3 in A-lo half, mi4-7 A-hi)
//   C cols  ni*64 + wn*16 + {0..15}, ni=0..3  (ni0-1 in B-lo half, ni2-3 B-hi)
// => P0 touches ONLY lo halves for every wave; half-readiness matches vmcnt ledger.
// LDS: [2 dbuf][2 half][128][64] per operand = 128 KiB. 16B-chunk swizzle:
// phys_chunk = logical ^ (row&7), both sides.
// If BF16OUT and vtOut != nullptr, columns c >= 2*HDIM also write the
// transposed V panel: Vt[(c-6144)][r0..r0+3] (one 8B store per (mi,ni)).
template <bool BF16OUT>
__global__ __launch_bounds__(512, 2) void gemm256(const u16* __restrict__ A,
                                                  const u16* __restrict__ B,
                                                  const float* __restrict__ bias,
                                                  float* __restrict__ outF,
                                                  u16* __restrict__ outB,
                                                  u16* __restrict__ vtOut,
                                                  int N, int K) {
  __shared__ __align__(16) u16 As[2][2][128][64];
  __shared__ __align__(16) u16 Bs[2][2][128][64];
  const int tid = threadIdx.x;
  const int w = tid >> 6, l = tid & 63;
  const int wm = w >> 2, wn = w & 3;
  const int fr = l & 15, g = l >> 4;
  // XCD-band mapping (hardware round-robin bid->XCD = bid%8); nbm = 32 = 8x4.
  const int xcd = blockIdx.x & 7, loc = blockIdx.x >> 3;
  const int bn = loc >> 2, bm = xcd * 4 + (loc & 3);

  // Staging: thread t writes half bytes t*16 and 8192+t*16
  //  -> rows t>>3 and 64+(t>>3), phys chunk t&7; source chunk inverse-swizzled.
  const int srow = tid >> 3;
  const int lc = (tid & 7) ^ ((tid >> 3) & 7);
  const u16* sA0 = A + (size_t)(bm * 256 + srow) * K + lc * 8;
  const u16* sA1 = sA0 + (size_t)64 * K;
  const u16* sB0 = B + (size_t)(bn * 256 + srow) * K + lc * 8;
  const u16* sB1 = sB0 + (size_t)64 * K;
  const size_t hiK = (size_t)128 * K;
  const int t16 = tid * 16;
  char* Aw = (char*)As;
  char* Bw = (char*)Bs;

  // Fragment read offsets (bytes within a [128][64] half):
  //  A row = mi*32 + wm*16 + fr ; B row = (ni&1)*64 + wn*16 + fr
  //  chunk = (kk*4+g) ^ (row&7); row&7 == fr&7 for all fragments.
  int rbA[4], rbB[2], ck[2];
#pragma unroll
  for (int i = 0; i < 4; ++i) rbA[i] = (i * 32 + wm * 16 + fr) * 128;
  rbB[0] = (wn * 16 + fr) * 128;
  rbB[1] = (64 + wn * 16 + fr) * 128;
  ck[0] = ((g) ^ (fr & 7)) * 16;
  ck[1] = ((4 + g) ^ (fr & 7)) * 16;

  f32x4 acc[8][4];
#pragma unroll
  for (int i = 0; i < 8; ++i)
#pragma unroll
    for (int j = 0; j < 4; ++j) acc[i][j] = (f32x4){0.f, 0.f, 0.f, 0.f};

  // prologue: stage tile0 (Alo,Blo,Bhi,Ahi) into parity 0
  gload_lds16(sA0, Aw + t16); gload_lds16(sA1, Aw + 8192 + t16);
  gload_lds16(sB0, Bw + t16); gload_lds16(sB1, Bw + 8192 + t16);
  gload_lds16(sB0 + hiK, Bw + 16384 + t16); gload_lds16(sB1 + hiK, Bw + 16384 + 8192 + t16);
  gload_lds16(sA0 + hiK, Aw + 16384 + t16); gload_lds16(sA1 + hiK, Aw + 16384 + 8192 + t16);
  sA0 += 64; sA1 += 64; sB0 += 64; sB1 += 64;  // -> tile 1
  asm volatile("s_waitcnt vmcnt(4)" ::: "memory");
  __builtin_amdgcn_s_barrier();
  __builtin_amdgcn_sched_barrier(0);

  const int NT = K >> 6;
  for (int T = 0; T < NT; ++T) {
    const int cur = T & 1, pp = (T + 1) & 1;
    const bool ds = (T + 1 < NT);
    const bool last = (T == NT - 1);
    const char* ah = (const char*)As + cur * 32768;
    const char* bh = (const char*)Bs + cur * 32768;
    char* apw = Aw + pp * 32768;
    char* bpw = Bw + pp * 32768;
    bf16x8 af[4][2], bf[4][2];

    // ---------------- P0 ----------------
#pragma unroll
    for (int mi = 0; mi < 4; ++mi)
#pragma unroll
      for (int kk = 0; kk < 2; ++kk)
        af[mi][kk] = *(const bf16x8*)(ah + rbA[mi] + ck[kk]);
#pragma unroll
    for (int ni = 0; ni < 2; ++ni)
#pragma unroll
      for (int kk = 0; kk < 2; ++kk)
        bf[ni][kk] = *(const bf16x8*)(bh + rbB[ni] + ck[kk]);
    if (ds) { gload_lds16(sA0, apw + t16); gload_lds16(sA1, apw + 8192 + t16); }
    __builtin_amdgcn_s_barrier();
    asm volatile("s_waitcnt lgkmcnt(0)" ::: "memory");
    __builtin_amdgcn_sched_barrier(0);
    __builtin_amdgcn_s_setprio(1);
#pragma unroll
    for (int kk = 0; kk < 2; ++kk)
#pragma unroll
      for (int mi = 0; mi < 4; ++mi)
#pragma unroll
        for (int ni = 0; ni < 2; ++ni)
          acc[mi][ni] = __builtin_amdgcn_mfma_f32_16x16x32_bf16(af[mi][kk], bf[ni][kk], acc[mi][ni], 0, 0, 0);
    __builtin_amdgcn_s_setprio(0);
    if (last) asm volatile("s_waitcnt vmcnt(2)" ::: "memory");
    else      asm volatile("s_waitcnt vmcnt(4)" ::: "memory");
    __builtin_amdgcn_s_barrier();

    // ---------------- P1 ----------------
#pragma unroll
    for (int ni = 2; ni < 4; ++ni)
#pragma unroll
      for (int kk = 0; kk < 2; ++kk)
        bf[ni][kk] = *(const bf16x8*)(bh + 16384 + rbB[ni - 2] + ck[kk]);
    if (ds) { gload_lds16(sB0, bpw + t16); gload_lds16(sB1, bpw + 8192 + t16); }
    __builtin_amdgcn_s_barrier();
    asm volatile("s_waitcnt lgkmcnt(0)" ::: "memory");
    __builtin_amdgcn_sched_barrier(0);
    __builtin_amdgcn_s_setprio(1);
#pragma unroll
    for (int kk = 0; kk < 2; ++kk)
#pragma unroll
      for (int mi = 0; mi < 4; ++mi)
#pragma unroll
        for (int ni = 2; ni < 4; ++ni)
          acc[mi][ni] = __builtin_amdgcn_mfma_f32_16x16x32_bf16(af[mi][kk], bf[ni][kk], acc[mi][ni], 0, 0, 0);
    __builtin_amdgcn_s_setprio(0);
    if (last) asm volatile("s_waitcnt vmcnt(0)" ::: "memory");
    else      asm volatile("s_waitcnt vmcnt(4)" ::: "memory");
    __builtin_amdgcn_s_barrier();

    // ---------------- P2 ----------------
#pragma unroll
    for (int mi = 0; mi < 4; ++mi)
#pragma unroll
      for (int kk = 0; kk < 2; ++kk)
        af[mi][kk] = *(const bf16x8*)(ah + 16384 + rbA[mi] + ck[kk]);
    if (ds) { gload_lds16(sB0 + hiK, bpw + 16384 + t16); gload_lds16(sB1 + hiK, bpw + 16384 + 8192 + t16); }
    __builtin_amdgcn_s_barrier();
    asm volatile("s_waitcnt lgkmcnt(0)" ::: "memory");
    __builtin_amdgcn_sched_barrier(0);
    __builtin_amdgcn_s_setprio(1);
#pragma unroll
    for (int kk = 0; kk < 2; ++kk)
#pragma unroll
      for (int mi = 0; mi < 4; ++mi)
#pragma unroll
        for (int ni = 0; ni < 2; ++ni)
          acc[mi + 4][ni] = __builtin_amdgcn_mfma_f32_16x16x32_bf16(af[mi][kk], bf[ni][kk], acc[mi + 4][ni], 0, 0, 0);
    __builtin_amdgcn_s_setprio(0);
    __builtin_amdgcn_s_barrier();

    // ---------------- P3 ----------------
    if (ds) { gload_lds16(sA0 + hiK, apw + 16384 + t16); gload_lds16(sA1 + hiK, apw + 16384 + 8192 + t16); }
    __builtin_amdgcn_s_barrier();
    __builtin_amdgcn_s_setprio(1);
#pragma unroll
    for (int kk = 0; kk < 2; ++kk)
#pragma unroll
      for (int mi = 0; mi < 4; ++mi)
#pragma unroll
        for (int ni = 2; ni < 4; ++ni)
          acc[mi + 4][ni] = __builtin_amdgcn_mfma_f32_16x16x32_bf16(af[mi][kk], bf[ni][kk], acc[mi + 4][ni], 0, 0, 0);
    __builtin_amdgcn_s_setprio(0);
    if (!last) asm volatile("s_waitcnt vmcnt(4)" ::: "memory");
    __builtin_amdgcn_s_barrier();
    if (ds) { sA0 += 64; sA1 += 64; sB0 += 64; sB1 += 64; }
    __builtin_amdgcn_sched_barrier(0);
  }

  // epilogue (+ optional fused V-transpose write)
#pragma unroll
  for (int ni = 0; ni < 4; ++ni) {
    const int c = bn * 256 + ni * 64 + wn * 16 + fr;
    const float bvv = bias ? bias[c] : 0.0f;
    const bool wv = BF16OUT && (vtOut != nullptr) && (c >= 2 * HDIM);
#pragma unroll
    for (int mi = 0; mi < 8; ++mi) {
      const int r0 = bm * 256 + mi * 32 + wm * 16 + g * 4;
      u16 t4[4];
#pragma unroll
      for (int jj = 0; jj < 4; ++jj) {
        float v = acc[mi][ni][jj] + bvv;
        if (BF16OUT) { u16 b_ = f2b(v); outB[(size_t)(r0 + jj) * N + c] = b_; t4[jj] = b_; }
        else         outF[(size_t)(r0 + jj) * N + c] = v;
      }
      if (wv) *(uint2*)(vtOut + (size_t)(c - 2 * HDIM) * SEQ + r0) = *(const uint2*)t4;
    }
  }
}

// ---------------- windowed flash attention: LDS-staged, 32 q-rows/wave ----------------
// grid (4 qb, 12 h, 19 win), 4 waves x 32 q-rows (2 row-groups of 16);
// 8 kv-chunks of 64. LDS: Ks 32KB + Vts 32KB + Ps[4][32*64] 16KB = 80KB
// -> 2 blocks/CU. Staging/swizzles byte-identical to the R1-proven kernel.
// Intensity fix: V fragments are read ONCE per (dn,kc) and feed BOTH row-
// groups' MFMAs (128 MFMA per wave-kt vs 64 at same V/LDS read volume).
// QK^T runs per-row-group sequentially to keep sacc at 16 VGPRs (total ~235).
// Barriers: 2 per kt (post-stage, end-of-kt). Ps is wave-private: same-wave
// ds ordering via lgkmcnt(0)+sched_barrier(0) (rule #18).
__global__ __launch_bounds__(256, 2) void attn_kernel(const u16* __restrict__ QKV,
                                                      const u16* __restrict__ Vt,
                                                      u16* __restrict__ ctxw) {
  __shared__ __align__(16) u16 Ks[64 * 256];   // [kv][d], chunk-swizzled (XOR row&31)
  __shared__ __align__(16) u16 Vts[256 * 64];  // [d][kv], chunk-swizzled (XOR row&7)
  __shared__ __align__(16) u16 Ps[4][32 * 64]; // per-wave P, XOR (q&7)<<4 byte swizzle
  const int qb = blockIdx.x, h = blockIdx.y, n = blockIdx.z;
  const int tid = threadIdx.x, w = tid >> 6, l = tid & 63;
  const int g = l >> 4, fr = l & 15;
  const int s0 = n * STR;

  // Q fragments: 2 row-groups x 16 rows per wave
  bf16x8 qf[2][8];
#pragma unroll
  for (int rg = 0; rg < 2; ++rg) {
    int sq = s0 + qb * 128 + w * 32 + rg * 16 + fr;
    if (sq > SEQ - 1) sq = SEQ - 1;
    const u16* qbase = QKV + (size_t)sq * QKVN + h * DHEAD + g * 8;
#pragma unroll
    for (int dc = 0; dc < 8; ++dc) qf[rg][dc] = *(const bf16x8*)(qbase + dc * 32);
  }
  f32x4 ctx[2][16];
#pragma unroll
  for (int rg = 0; rg < 2; ++rg)
#pragma unroll
    for (int dn = 0; dn < 16; ++dn) ctx[rg][dn] = (f32x4){0.f, 0.f, 0.f, 0.f};
  float mrow[2][4], lrow[2][4];
#pragma unroll
  for (int rg = 0; rg < 2; ++rg)
#pragma unroll
    for (int r = 0; r < 4; ++r) { mrow[rg][r] = -3e38f; lrow[rg][r] = 0.f; }

  const int kr_in = l >> 5;  // K staging: row within 2-row chunk
  const int kcp = l & 31;    // K staging: physical 16B chunk in row
  const int vr_in = l >> 3;  // V staging: row within 8-row chunk
  const int vcp = l & 7;
  char* pw = (char*)&Ps[w][0];

  for (int kt = 0; kt < 8; ++kt) {
    const int sb = s0 + kt * 64;
    // ---- stage K[64][256] and Vt-slice[256][64], source pre-swizzled ----
#pragma unroll
    for (int i = 0; i < 8; ++i) {
      const int c = i * 4 + w;  // 1KB chunk id, 0..31
      {
        const int krow = c * 2 + kr_in;
        const int cl = kcp ^ (krow & 31);
        int sk = sb + krow;
        if (sk > SEQ - 1) sk = SEQ - 1;
        gload_lds16(QKV + (size_t)sk * QKVN + HDIM + h * DHEAD + cl * 8, (char*)Ks + c * 1024);
      }
      {
        const int d = c * 8 + vr_in;
        const int cl = vcp ^ (d & 7);
        int sv = sb + cl * 8;
        if (sv > SEQ - 8) sv = SEQ - 8;
        gload_lds16(Vt + (size_t)(h * DHEAD + d) * SEQ + sv, (char*)Vts + c * 1024);
      }
    }
    __syncthreads();  // staging drained (vmcnt0+barrier) before any read

    // ---- per row-group: S = Q K^T, softmax, Ps write ----
#pragma unroll
    for (int rg = 0; rg < 2; ++rg) {
      f32x4 sacc[4];
#pragma unroll
      for (int kn = 0; kn < 4; ++kn) sacc[kn] = (f32x4){0.f, 0.f, 0.f, 0.f};
#pragma unroll
      for (int kn = 0; kn < 4; ++kn) {
        const int krow = kn * 16 + fr;
        const char* krp = (const char*)Ks + krow * 512;
        const int rx = krow & 31;
#pragma unroll
        for (int dc = 0; dc < 8; ++dc) {
          bf16x8 kf = *(const bf16x8*)(krp + (((dc * 4 + g) ^ rx) << 4));
          sacc[kn] = __builtin_amdgcn_mfma_f32_16x16x32_bf16(qf[rg][dc], kf, sacc[kn], 0, 0, 0);
        }
      }
      // scale + validity mask + online softmax
      float mt[4];
#pragma unroll
      for (int kn = 0; kn < 4; ++kn) {
        const bool valid = (sb + kn * 16 + fr) < SEQ;
#pragma unroll
        for (int r = 0; r < 4; ++r) {
          float v = valid ? sacc[kn][r] * ATTN_SCALE : -1e9f;
          sacc[kn][r] = v;
          mt[r] = (kn == 0) ? v : fmaxf(mt[r], v);
        }
      }
#pragma unroll
      for (int r = 0; r < 4; ++r) {
#pragma unroll
        for (int off = 1; off < 16; off <<= 1)
          mt[r] = fmaxf(mt[r], __shfl_xor(mt[r], off, 64));
      }
      float corr[4];
#pragma unroll
      for (int r = 0; r < 4; ++r) {
        float mnew = fmaxf(mrow[rg][r], mt[r]);
        corr[r] = __expf(mrow[rg][r] - mnew);
        mrow[rg][r] = mnew;
      }
      float psum[4] = {0.f, 0.f, 0.f, 0.f};
#pragma unroll
      for (int kn = 0; kn < 4; ++kn) {
#pragma unroll
        for (int r = 0; r < 4; ++r) {
          float p = __expf(sacc[kn][r] - mrow[rg][r]);
          psum[r] += p;
          const int q = rg * 16 + g * 4 + r;
          *(u16*)(pw + q * 128 + ((2 * (kn * 16 + fr)) ^ ((q & 7) << 4))) = f2b(p);
        }
      }
#pragma unroll
      for (int r = 0; r < 4; ++r) {
#pragma unroll
        for (int off = 1; off < 16; off <<= 1)
          psum[r] += __shfl_xor(psum[r], off, 64);
        lrow[rg][r] = lrow[rg][r] * corr[r] + psum[r];
      }
#pragma unroll
      for (int dn = 0; dn < 16; ++dn)
#pragma unroll
        for (int r = 0; r < 4; ++r) ctx[rg][dn][r] *= corr[r];
    }
    // same-wave ds_write -> ds_read ordering for wave-private Ps (rule #18)
    asm volatile("s_waitcnt lgkmcnt(0)" ::: "memory");
    __builtin_amdgcn_sched_barrier(0);

    // ---- ctx += P * V ; V fragment read once, feeds both row-groups ----
    bf16x8 pf[2][2];
#pragma unroll
    for (int rg = 0; rg < 2; ++rg)
#pragma unroll
      for (int kc = 0; kc < 2; ++kc)
        pf[rg][kc] = *(const bf16x8*)(pw + (rg * 16 + fr) * 128 +
                                      ((kc * 64 + g * 16) ^ ((fr & 7) << 4)));
#pragma unroll
    for (int dn = 0; dn < 16; ++dn) {
      const int d = dn * 16 + fr;
      const char* vrp = (const char*)Vts + d * 128;
      const int dx = d & 7;
#pragma unroll
      for (int kc = 0; kc < 2; ++kc) {
        bf16x8 vf = *(const bf16x8*)(vrp + (((kc * 4 + g) ^ dx) << 4));
        ctx[0][dn] = __builtin_amdgcn_mfma_f32_16x16x32_bf16(pf[0][kc], vf, ctx[0][dn], 0, 0, 0);
        ctx[1][dn] = __builtin_amdgcn_mfma_f32_16x16x32_bf16(pf[1][kc], vf, ctx[1][dn], 0, 0, 0);
      }
    }
    __syncthreads();  // all waves done with Ks/Vts before next stage
  }
  // ---- epilogue: normalize and store ctx ----
#pragma unroll
  for (int rg = 0; rg < 2; ++rg) {
    float inv[4];
#pragma unroll
    for (int r = 0; r < 4; ++r) inv[r] = 1.0f / lrow[rg][r];
    const int qrow0 = qb * 128 + w * 32 + rg * 16 + g * 4;
#pragma unroll
    for (int dn = 0; dn < 16; ++dn) {
#pragma unroll
      for (int r = 0; r < 4; ++r) {
        ctxw[(size_t)(n * WINL + qrow0 + r) * HDIM + h * DHEAD + dn * 16 + fr] =
            f2b(ctx[rg][dn][r] * inv[r]);
      }
    }
  }
}

// ---------------- overlap-average combine: ctx_avg[8192][3072] ----------------
__global__ __launch_bounds__(256) void combine_kernel(const u16* __restrict__ ctxw,
                                                      u16* __restrict__ ctx_avg) {
  int idx = blockIdx.x * 256 + threadIdx.x;
  if (idx >= SEQ * (HDIM / 8)) return;
  const int s = idx / (HDIM / 8);
  const int cc = (idx % (HDIM / 8)) * 8;
  const int w1 = s / STR;          // <= 18
  const int off1 = s - w1 * STR;   // 0..447
  us8 a = *(const us8*)(ctxw + (size_t)(w1 * WINL + off1) * HDIM + cc);
  if (w1 >= 1 && off1 < (WINL - STR)) {
    us8 b = *(const us8*)(ctxw + (size_t)((w1 - 1) * WINL + off1 + STR) * HDIM + cc);
#pragma unroll
    for (int j = 0; j < 8; ++j) a[j] = f2b(0.5f * (b2f(a[j]) + b2f(b[j])));
  }
  *(us8*)(ctx_avg + (size_t)s * HDIM + cc) = a;
}

__global__ void ws_marker(float* out, float v) { out[0] = v; }

// ---------------- launch ----------------
extern "C" void kernel_launch(void* const* d_in, const int* in_sizes, int n_in,
                              void* d_out, int out_size, void* d_ws, size_t ws_size,
                              hipStream_t stream) {
  const float* X  = (const float*)d_in[0];
  const float* Wq = (const float*)d_in[1];
  const float* bq = (const float*)d_in[2];
  const float* Wk = (const float*)d_in[3];
  const float* bk = (const float*)d_in[4];
  const float* Wv = (const float*)d_in[5];
  const float* bv = (const float*)d_in[6];
  const float* Wo = (const float*)d_in[7];
  const float* bo = (const float*)d_in[8];
  float* out = (float*)d_out;

  // workspace layout (bytes)
  const size_t OFF_XB   = 0;                          // 8192*3072*2   = 50331648
  const size_t OFF_WQKV = 50331648;                   // 9216*3072*2   = 56623104
  const size_t OFF_WO   = 106954752;                  // 3072*3072*2   = 18874368
  const size_t OFF_QKV  = 125829120;                  // 8192*9216*2   = 150994944
  const size_t OFF_VT   = 276824064;                  // 3072*8192*2   = 50331648
  const size_t OFF_BIAS = 327155712;                  // 9216*4        = 36864
  const size_t WS_NEED  = 327192576;
  if (ws_size < WS_NEED) {
    hipMemsetAsync(d_out, 0, (size_t)out_size * 4, stream);
    ws_marker<<<1, 1, 0, stream>>>(out, (float)(ws_size / 1048576));
    return;
  }
  char* ws = (char*)d_ws;
  u16* Xb      = (u16*)(ws + OFF_XB);
  u16* Wqkvb   = (u16*)(ws + OFF_WQKV);
  u16* Wob     = (u16*)(ws + OFF_WO);
  u16* QKV     = (u16*)(ws + OFF_QKV);
  u16* Vt      = (u16*)(ws + OFF_VT);
  float* biasQ = (float*)(ws + OFF_BIAS);
  u16* ctxw    = (u16*)d_out;  // 59.8MB scratch inside the 100.7MB output buffer
  u16* ctx_avg = Xb;           // alias: Xb dead after QKV GEMM

  cvt_f32_bf16<<<12288, 256, 0, stream>>>(X, Xb, SEQ * HDIM / 8);
  cvt_f32_bf16<<<4608, 256, 0, stream>>>(Wq, Wqkvb, HDIM * HDIM / 8);
  cvt_f32_bf16<<<4608, 256, 0, stream>>>(Wk, Wqkvb + (size_t)HDIM * HDIM, HDIM * HDIM / 8);
  cvt_f32_bf16<<<4608, 256, 0, stream>>>(Wv, Wqkvb + (size_t)2 * HDIM * HDIM, HDIM * HDIM / 8);
  cvt_f32_bf16<<<4608, 256, 0, stream>>>(Wo, Wob, HDIM * HDIM / 8);
  biascat<<<36, 256, 0, stream>>>(bq, bk, bv, biasQ);

  gemm256<true><<<dim3((SEQ / 256) * (QKVN / 256)), 512, 0, stream>>>(
      Xb, Wqkvb, biasQ, nullptr, QKV, Vt, QKVN, HDIM);

  attn_kernel<<<dim3(4, NHEAD, NWIN), 256, 0, stream>>>(QKV, Vt, ctxw);

  combine_kernel<<<12288, 256, 0, stream>>>(ctxw, ctx_avg);

  gemm256<false><<<dim3((SEQ / 256) * (HDIM / 256)), 512, 0, stream>>>(
      ctx_avg, Wob, bo, out, nullptr, nullptr, HDIM, HDIM);
}

// Round 12
// 851.418 us; speedup vs baseline: 1.4445x; 1.2267x over previous
//
#include <hip/hip_runtime.h>
#include <hip/hip_bf16.h>
#include <stdint.h>

// Problem constants
#define SEQ   8192
#define HDIM  3072
#define NWIN  19
#define WINL  512
#define STR   448
#define NHEAD 12
#define DHEAD 256
#define QKVN  9216
#define ATTN_SCALE 0.0625f

typedef unsigned short u16;
typedef __bf16 bf16x8 __attribute__((ext_vector_type(8)));
typedef float  f32x4  __attribute__((ext_vector_type(4)));
typedef unsigned short us8 __attribute__((ext_vector_type(8)));

__device__ __forceinline__ u16 f2b(float x) {
  return __builtin_bit_cast(u16, __float2bfloat16(x));
}
__device__ __forceinline__ float b2f(u16 u) {
  return __builtin_bit_cast(float, (unsigned int)(u) << 16);
}
__device__ __forceinline__ void gload_lds16(const void* g, void* l) {
  __builtin_amdgcn_global_load_lds(
      (const __attribute__((address_space(1))) void*)g,
      (__attribute__((address_space(3))) void*)l, 16, 0, 0);
}

// ---------------- elementwise converts ----------------
__global__ __launch_bounds__(256) void cvt_f32_bf16(const float* __restrict__ src,
                                                    u16* __restrict__ dst, int n8) {
  int i = blockIdx.x * 256 + threadIdx.x;
  if (i >= n8) return;
  const float4* s4 = (const float4*)src;
  float4 a = s4[2 * i], b = s4[2 * i + 1];
  us8 o;
  o[0] = f2b(a.x); o[1] = f2b(a.y); o[2] = f2b(a.z); o[3] = f2b(a.w);
  o[4] = f2b(b.x); o[5] = f2b(b.y); o[6] = f2b(b.z); o[7] = f2b(b.w);
  *((us8*)dst + i) = o;
}

__global__ __launch_bounds__(256) void biascat(const float* __restrict__ bq,
                                               const float* __restrict__ bk,
                                               const float* __restrict__ bv,
                                               float* __restrict__ dst) {
  int i = blockIdx.x * 256 + threadIdx.x;
  if (i >= QKVN) return;
  dst[i] = (i < HDIM) ? bq[i] : ((i < 2 * HDIM) ? bk[i - HDIM] : bv[i - 2 * HDIM]);
}

// ---------------- 256x256 8-phase GEMM (R4-exact): C = A * B^T (+bias) ----------------
// A[M][K] bf16 row-major, B[N][K] bf16 row-major. K-tile BK=64.
// 8 waves (2Mx4N). INTERLEAVED ownership (correctness-critical):
//   C rows  mi*32 + wm*16 + {0..15}, mi=0..7  (mi0-3 in A-lo half, mi4-7 A-hi)
//   C cols  ni*64 + wn*16 + {0..15}, ni=0..3  (ni0-1 in B-lo half, ni2-3 B-hi)
// => P0 touches ONLY lo halves for every wave; half-readiness matches vmcnt ledger.
// LDS: [2 dbuf][2 half][128][64] per operand = 128 KiB. 16B-chunk swizzle:
// phys_chunk = logical ^ (row&7), both sides.
// If BF16OUT and vtOut != nullptr, columns c >= 2*HDIM also write the
// transposed V panel: Vt[(c-6144)][r0..r0+3] (one 8B store per (mi,ni)).
template <bool BF16OUT>
__global__ __launch_bounds__(512, 2) void gemm256(const u16* __restrict__ A,
                                                  const u16* __restrict__ B,
                                                  const float* __restrict__ bias,
                                                  float* __restrict__ outF,
                                                  u16* __restrict__ outB,
                                                  u16* __restrict__ vtOut,
                                                  int N, int K) {
  __shared__ __align__(16) u16 As[2][2][128][64];
  __shared__ __align__(16) u16 Bs[2][2][128][64];
  const int tid = threadIdx.x;
  const int w = tid >> 6, l = tid & 63;
  const int wm = w >> 2, wn = w & 3;
  const int fr = l & 15, g = l >> 4;
  // XCD-band mapping (hardware round-robin bid->XCD = bid%8); nbm = 32 = 8x4.
  const int xcd = blockIdx.x & 7, loc = blockIdx.x >> 3;
  const int bn = loc >> 2, bm = xcd * 4 + (loc & 3);

  // Staging: thread t writes half bytes t*16 and 8192+t*16
  //  -> rows t>>3 and 64+(t>>3), phys chunk t&7; source chunk inverse-swizzled.
  const int srow = tid >> 3;
  const int lc = (tid & 7) ^ ((tid >> 3) & 7);
  const u16* sA0 = A + (size_t)(bm * 256 + srow) * K + lc * 8;
  const u16* sA1 = sA0 + (size_t)64 * K;
  const u16* sB0 = B + (size_t)(bn * 256 + srow) * K + lc * 8;
  const u16* sB1 = sB0 + (size_t)64 * K;
  const size_t hiK = (size_t)128 * K;
  const int t16 = tid * 16;
  char* Aw = (char*)As;
  char* Bw = (char*)Bs;

  // Fragment read offsets (bytes within a [128][64] half):
  //  A row = mi*32 + wm*16 + fr ; B row = (ni&1)*64 + wn*16 + fr
  //  chunk = (kk*4+g) ^ (row&7); row&7 == fr&7 for all fragments.
  int rbA[4], rbB[2], ck[2];
#pragma unroll
  for (int i = 0; i < 4; ++i) rbA[i] = (i * 32 + wm * 16 + fr) * 128;
  rbB[0] = (wn * 16 + fr) * 128;
  rbB[1] = (64 + wn * 16 + fr) * 128;
  ck[0] = ((g) ^ (fr & 7)) * 16;
  ck[1] = ((4 + g) ^ (fr & 7)) * 16;

  f32x4 acc[8][4];
#pragma unroll
  for (int i = 0; i < 8; ++i)
#pragma unroll
    for (int j = 0; j < 4; ++j) acc[i][j] = (f32x4){0.f, 0.f, 0.f, 0.f};

  // prologue: stage tile0 (Alo,Blo,Bhi,Ahi) into parity 0
  gload_lds16(sA0, Aw + t16); gload_lds16(sA1, Aw + 8192 + t16);
  gload_lds16(sB0, Bw + t16); gload_lds16(sB1, Bw + 8192 + t16);
  gload_lds16(sB0 + hiK, Bw + 16384 + t16); gload_lds16(sB1 + hiK, Bw + 16384 + 8192 + t16);
  gload_lds16(sA0 + hiK, Aw + 16384 + t16); gload_lds16(sA1 + hiK, Aw + 16384 + 8192 + t16);
  sA0 += 64; sA1 += 64; sB0 += 64; sB1 += 64;  // -> tile 1
  asm volatile("s_waitcnt vmcnt(4)" ::: "memory");
  __builtin_amdgcn_s_barrier();
  __builtin_amdgcn_sched_barrier(0);

  const int NT = K >> 6;
  for (int T = 0; T < NT; ++T) {
    const int cur = T & 1, pp = (T + 1) & 1;
    const bool ds = (T + 1 < NT);
    const bool last = (T == NT - 1);
    const char* ah = (const char*)As + cur * 32768;
    const char* bh = (const char*)Bs + cur * 32768;
    char* apw = Aw + pp * 32768;
    char* bpw = Bw + pp * 32768;
    bf16x8 af[4][2], bf[4][2];

    // ---------------- P0 ----------------
#pragma unroll
    for (int mi = 0; mi < 4; ++mi)
#pragma unroll
      for (int kk = 0; kk < 2; ++kk)
        af[mi][kk] = *(const bf16x8*)(ah + rbA[mi] + ck[kk]);
#pragma unroll
    for (int ni = 0; ni < 2; ++ni)
#pragma unroll
      for (int kk = 0; kk < 2; ++kk)
        bf[ni][kk] = *(const bf16x8*)(bh + rbB[ni] + ck[kk]);
    if (ds) { gload_lds16(sA0, apw + t16); gload_lds16(sA1, apw + 8192 + t16); }
    __builtin_amdgcn_s_barrier();
    asm volatile("s_waitcnt lgkmcnt(0)" ::: "memory");
    __builtin_amdgcn_sched_barrier(0);
    __builtin_amdgcn_s_setprio(1);
#pragma unroll
    for (int kk = 0; kk < 2; ++kk)
#pragma unroll
      for (int mi = 0; mi < 4; ++mi)
#pragma unroll
        for (int ni = 0; ni < 2; ++ni)
          acc[mi][ni] = __builtin_amdgcn_mfma_f32_16x16x32_bf16(af[mi][kk], bf[ni][kk], acc[mi][ni], 0, 0, 0);
    __builtin_amdgcn_s_setprio(0);
    if (last) asm volatile("s_waitcnt vmcnt(2)" ::: "memory");
    else      asm volatile("s_waitcnt vmcnt(4)" ::: "memory");
    __builtin_amdgcn_s_barrier();

    // ---------------- P1 ----------------
#pragma unroll
    for (int ni = 2; ni < 4; ++ni)
#pragma unroll
      for (int kk = 0; kk < 2; ++kk)
        bf[ni][kk] = *(const bf16x8*)(bh + 16384 + rbB[ni - 2] + ck[kk]);
    if (ds) { gload_lds16(sB0, bpw + t16); gload_lds16(sB1, bpw + 8192 + t16); }
    __builtin_amdgcn_s_barrier();
    asm volatile("s_waitcnt lgkmcnt(0)" ::: "memory");
    __builtin_amdgcn_sched_barrier(0);
    __builtin_amdgcn_s_setprio(1);
#pragma unroll
    for (int kk = 0; kk < 2; ++kk)
#pragma unroll
      for (int mi = 0; mi < 4; ++mi)
#pragma unroll
        for (int ni = 2; ni < 4; ++ni)
          acc[mi][ni] = __builtin_amdgcn_mfma_f32_16x16x32_bf16(af[mi][kk], bf[ni][kk], acc[mi][ni], 0, 0, 0);
    __builtin_amdgcn_s_setprio(0);
    if (last) asm volatile("s_waitcnt vmcnt(0)" ::: "memory");
    else      asm volatile("s_waitcnt vmcnt(4)" ::: "memory");
    __builtin_amdgcn_s_barrier();

    // ---------------- P2 ----------------
#pragma unroll
    for (int mi = 0; mi < 4; ++mi)
#pragma unroll
      for (int kk = 0; kk < 2; ++kk)
        af[mi][kk] = *(const bf16x8*)(ah + 16384 + rbA[mi] + ck[kk]);
    if (ds) { gload_lds16(sB0 + hiK, bpw + 16384 + t16); gload_lds16(sB1 + hiK, bpw + 16384 + 8192 + t16); }
    __builtin_amdgcn_s_barrier();
    asm volatile("s_waitcnt lgkmcnt(0)" ::: "memory");
    __builtin_amdgcn_sched_barrier(0);
    __builtin_amdgcn_s_setprio(1);
#pragma unroll
    for (int kk = 0; kk < 2; ++kk)
#pragma unroll
      for (int mi = 0; mi < 4; ++mi)
#pragma unroll
        for (int ni = 0; ni < 2; ++ni)
          acc[mi + 4][ni] = __builtin_amdgcn_mfma_f32_16x16x32_bf16(af[mi][kk], bf[ni][kk], acc[mi + 4][ni], 0, 0, 0);
    __builtin_amdgcn_s_setprio(0);
    __builtin_amdgcn_s_barrier();

    // ---------------- P3 ----------------
    if (ds) { gload_lds16(sA0 + hiK, apw + 16384 + t16); gload_lds16(sA1 + hiK, apw + 16384 + 8192 + t16); }
    __builtin_amdgcn_s_barrier();
    __builtin_amdgcn_s_setprio(1);
#pragma unroll
    for (int kk = 0; kk < 2; ++kk)
#pragma unroll
      for (int mi = 0; mi < 4; ++mi)
#pragma unroll
        for (int ni = 2; ni < 4; ++ni)
          acc[mi + 4][ni] = __builtin_amdgcn_mfma_f32_16x16x32_bf16(af[mi][kk], bf[ni][kk], acc[mi + 4][ni], 0, 0, 0);
    __builtin_amdgcn_s_setprio(0);
    if (!last) asm volatile("s_waitcnt vmcnt(4)" ::: "memory");
    __builtin_amdgcn_s_barrier();
    if (ds) { sA0 += 64; sA1 += 64; sB0 += 64; sB1 += 64; }
    __builtin_amdgcn_sched_barrier(0);
  }

  // epilogue (+ optional fused V-transpose write)
#pragma unroll
  for (int ni = 0; ni < 4; ++ni) {
    const int c = bn * 256 + ni * 64 + wn * 16 + fr;
    const float bvv = bias ? bias[c] : 0.0f;
    const bool wv = BF16OUT && (vtOut != nullptr) && (c >= 2 * HDIM);
#pragma unroll
    for (int mi = 0; mi < 8; ++mi) {
      const int r0 = bm * 256 + mi * 32 + wm * 16 + g * 4;
      u16 t4[4];
#pragma unroll
      for (int jj = 0; jj < 4; ++jj) {
        float v = acc[mi][ni][jj] + bvv;
        if (BF16OUT) { u16 b_ = f2b(v); outB[(size_t)(r0 + jj) * N + c] = b_; t4[jj] = b_; }
        else         outF[(size_t)(r0 + jj) * N + c] = v;
      }
      if (wv) *(uint2*)(vtOut + (size_t)(c - 2 * HDIM) * SEQ + r0) = *(const uint2*)t4;
    }
  }
}

// ---------------- windowed flash attention (R1-exact + wave-private-Ps fence) ----------------
// grid (8 qb, 12 h, 19 win), 4 waves. Each wave: 16 q-rows, online softmax over
// 8 chunks of 64 kv. LDS: Ks 32KB + Vts 32KB + Ps 8KB = 72KB -> 2 blocks/CU.
// 2 barriers/kt: post-stage (__syncthreads drains vmcnt) and end-of-kt.
// Ps is wave-private -> same-wave ds_write->ds_read ordered by lgkmcnt(0)
// + sched_barrier(0) (rule #18; validated in R9/R11 refchecks).
__global__ __launch_bounds__(256, 2) void attn_kernel(const u16* __restrict__ QKV,
                                                      const u16* __restrict__ Vt,
                                                      u16* __restrict__ ctxw) {
  __shared__ __align__(16) u16 Ks[64 * 256];   // [kv][d], chunk-swizzled (XOR row&31)
  __shared__ __align__(16) u16 Vts[256 * 64];  // [d][kv], chunk-swizzled (XOR row&7)
  __shared__ __align__(16) u16 Ps[4][16 * 64]; // per-wave P scratch, XOR (q&7)<<4
  const int qb = blockIdx.x, h = blockIdx.y, n = blockIdx.z;
  const int tid = threadIdx.x, w = tid >> 6, l = tid & 63;
  const int g = l >> 4, fr = l & 15;
  const int s0 = n * STR;

  // Q fragments (16 rows per wave) straight from global
  bf16x8 qf[8];
  {
    int sq = s0 + qb * 64 + w * 16 + fr;
    if (sq > SEQ - 1) sq = SEQ - 1;
    const u16* qbase = QKV + (size_t)sq * QKVN + h * DHEAD + g * 8;
#pragma unroll
    for (int dc = 0; dc < 8; ++dc) qf[dc] = *(const bf16x8*)(qbase + dc * 32);
  }
  f32x4 ctx[16];
#pragma unroll
  for (int dn = 0; dn < 16; ++dn) ctx[dn] = (f32x4){0.f, 0.f, 0.f, 0.f};
  float mrow[4] = {-3e38f, -3e38f, -3e38f, -3e38f};
  float lrow[4] = {0.f, 0.f, 0.f, 0.f};

  const int kr_in = l >> 5;  // K staging: row within 2-row chunk
  const int kcp = l & 31;    // K staging: physical 16B chunk in row
  const int vr_in = l >> 3;  // V staging: row within 8-row chunk
  const int vcp = l & 7;
  char* pw = (char*)&Ps[w][0];

  for (int kt = 0; kt < 8; ++kt) {
    const int sb = s0 + kt * 64;
    // ---- stage K[64][256] and Vt-slice[256][64], source pre-swizzled ----
#pragma unroll
    for (int i = 0; i < 8; ++i) {
      const int c = i * 4 + w;  // 1KB chunk id, 0..31
      {
        const int krow = c * 2 + kr_in;
        const int cl = kcp ^ (krow & 31);
        int sk = sb + krow;
        if (sk > SEQ - 1) sk = SEQ - 1;
        gload_lds16(QKV + (size_t)sk * QKVN + HDIM + h * DHEAD + cl * 8, (char*)Ks + c * 1024);
      }
      {
        const int d = c * 8 + vr_in;
        const int cl = vcp ^ (d & 7);
        int sv = sb + cl * 8;
        if (sv > SEQ - 8) sv = SEQ - 8;
        gload_lds16(Vt + (size_t)(h * DHEAD + d) * SEQ + sv, (char*)Vts + c * 1024);
      }
    }
    __syncthreads();

    // ---- S = Q K^T (rows q=(g*4+r), cols kv=kn*16+fr) ----
    f32x4 sacc[4];
#pragma unroll
    for (int kn = 0; kn < 4; ++kn) sacc[kn] = (f32x4){0.f, 0.f, 0.f, 0.f};
#pragma unroll
    for (int kn = 0; kn < 4; ++kn) {
      const int krow = kn * 16 + fr;
      const char* krp = (const char*)Ks + krow * 512;
      const int rx = krow & 31;
#pragma unroll
      for (int dc = 0; dc < 8; ++dc) {
        bf16x8 kf = *(const bf16x8*)(krp + (((dc * 4 + g) ^ rx) << 4));
        sacc[kn] = __builtin_amdgcn_mfma_f32_16x16x32_bf16(qf[dc], kf, sacc[kn], 0, 0, 0);
      }
    }
    // ---- scale + validity mask + online softmax ----
    float mt[4];
#pragma unroll
    for (int kn = 0; kn < 4; ++kn) {
      const bool valid = (sb + kn * 16 + fr) < SEQ;
#pragma unroll
      for (int r = 0; r < 4; ++r) {
        float v = valid ? sacc[kn][r] * ATTN_SCALE : -1e9f;
        sacc[kn][r] = v;
        mt[r] = (kn == 0) ? v : fmaxf(mt[r], v);
      }
    }
#pragma unroll
    for (int r = 0; r < 4; ++r) {
#pragma unroll
      for (int off = 1; off < 16; off <<= 1)
        mt[r] = fmaxf(mt[r], __shfl_xor(mt[r], off, 64));
    }
    float corr[4];
#pragma unroll
    for (int r = 0; r < 4; ++r) {
      float mnew = fmaxf(mrow[r], mt[r]);
      corr[r] = __expf(mrow[r] - mnew);
      mrow[r] = mnew;
    }
    float psum[4] = {0.f, 0.f, 0.f, 0.f};
#pragma unroll
    for (int kn = 0; kn < 4; ++kn) {
#pragma unroll
      for (int r = 0; r < 4; ++r) {
        float p = __expf(sacc[kn][r] - mrow[r]);
        psum[r] += p;
        const int q = g * 4 + r;
        *(u16*)(pw + q * 128 + ((2 * (kn * 16 + fr)) ^ ((q & 7) << 4))) = f2b(p);
      }
    }
#pragma unroll
    for (int r = 0; r < 4; ++r) {
#pragma unroll
      for (int off = 1; off < 16; off <<= 1)
        psum[r] += __shfl_xor(psum[r], off, 64);
      lrow[r] = lrow[r] * corr[r] + psum[r];
    }
#pragma unroll
    for (int dn = 0; dn < 16; ++dn)
#pragma unroll
      for (int r = 0; r < 4; ++r) ctx[dn][r] *= corr[r];
    // same-wave ds_write -> ds_read ordering for wave-private Ps (rule #18)
    asm volatile("s_waitcnt lgkmcnt(0)" ::: "memory");
    __builtin_amdgcn_sched_barrier(0);

    // ---- ctx += P * V (via Vt rows as B^T) ----
    bf16x8 pf[2];
#pragma unroll
    for (int kc = 0; kc < 2; ++kc)
      pf[kc] = *(const bf16x8*)(pw + fr * 128 + ((kc * 64 + g * 16) ^ ((fr & 7) << 4)));
#pragma unroll
    for (int dn = 0; dn < 16; ++dn) {
      const int d = dn * 16 + fr;
      const char* vrp = (const char*)Vts + d * 128;
      const int dx = d & 7;
#pragma unroll
      for (int kc = 0; kc < 2; ++kc) {
        bf16x8 vf = *(const bf16x8*)(vrp + (((kc * 4 + g) ^ dx) << 4));
        ctx[dn] = __builtin_amdgcn_mfma_f32_16x16x32_bf16(pf[kc], vf, ctx[dn], 0, 0, 0);
      }
    }
    __syncthreads();  // all waves done with Ks/Vts before next stage
  }
  // ---- epilogue: normalize and store ctx ----
  float inv[4];
#pragma unroll
  for (int r = 0; r < 4; ++r) inv[r] = 1.0f / lrow[r];
  const int qrow0 = qb * 64 + w * 16 + g * 4;
#pragma unroll
  for (int dn = 0; dn < 16; ++dn) {
#pragma unroll
    for (int r = 0; r < 4; ++r) {
      ctxw[(size_t)(n * WINL + qrow0 + r) * HDIM + h * DHEAD + dn * 16 + fr] =
          f2b(ctx[dn][r] * inv[r]);
    }
  }
}

// ---------------- overlap-average combine: ctx_avg[8192][3072] ----------------
__global__ __launch_bounds__(256) void combine_kernel(const u16* __restrict__ ctxw,
                                                      u16* __restrict__ ctx_avg) {
  int idx = blockIdx.x * 256 + threadIdx.x;
  if (idx >= SEQ * (HDIM / 8)) return;
  const int s = idx / (HDIM / 8);
  const int cc = (idx % (HDIM / 8)) * 8;
  const int w1 = s / STR;          // <= 18
  const int off1 = s - w1 * STR;   // 0..447
  us8 a = *(const us8*)(ctxw + (size_t)(w1 * WINL + off1) * HDIM + cc);
  if (w1 >= 1 && off1 < (WINL - STR)) {
    us8 b = *(const us8*)(ctxw + (size_t)((w1 - 1) * WINL + off1 + STR) * HDIM + cc);
#pragma unroll
    for (int j = 0; j < 8; ++j) a[j] = f2b(0.5f * (b2f(a[j]) + b2f(b[j])));
  }
  *(us8*)(ctx_avg + (size_t)s * HDIM + cc) = a;
}

__global__ void ws_marker(float* out, float v) { out[0] = v; }

// ---------------- launch ----------------
extern "C" void kernel_launch(void* const* d_in, const int* in_sizes, int n_in,
                              void* d_out, int out_size, void* d_ws, size_t ws_size,
                              hipStream_t stream) {
  const float* X  = (const float*)d_in[0];
  const float* Wq = (const float*)d_in[1];
  const float* bq = (const float*)d_in[2];
  const float* Wk = (const float*)d_in[3];
  const float* bk = (const float*)d_in[4];
  const float* Wv = (const float*)d_in[5];
  const float* bv = (const float*)d_in[6];
  const float* Wo = (const float*)d_in[7];
  const float* bo = (const float*)d_in[8];
  float* out = (float*)d_out;

  // workspace layout (bytes)
  const size_t OFF_XB   = 0;                          // 8192*3072*2   = 50331648
  const size_t OFF_WQKV = 50331648;                   // 9216*3072*2   = 56623104
  const size_t OFF_WO   = 106954752;                  // 3072*3072*2   = 18874368
  const size_t OFF_QKV  = 125829120;                  // 8192*9216*2   = 150994944
  const size_t OFF_VT   = 276824064;                  // 3072*8192*2   = 50331648
  const size_t OFF_BIAS = 327155712;                  // 9216*4        = 36864
  const size_t WS_NEED  = 327192576;
  if (ws_size < WS_NEED) {
    hipMemsetAsync(d_out, 0, (size_t)out_size * 4, stream);
    ws_marker<<<1, 1, 0, stream>>>(out, (float)(ws_size / 1048576));
    return;
  }
  char* ws = (char*)d_ws;
  u16* Xb      = (u16*)(ws + OFF_XB);
  u16* Wqkvb   = (u16*)(ws + OFF_WQKV);
  u16* Wob     = (u16*)(ws + OFF_WO);
  u16* QKV     = (u16*)(ws + OFF_QKV);
  u16* Vt      = (u16*)(ws + OFF_VT);
  float* biasQ = (float*)(ws + OFF_BIAS);
  u16* ctxw    = (u16*)d_out;  // 59.8MB scratch inside the 100.7MB output buffer
  u16* ctx_avg = Xb;           // alias: Xb dead after QKV GEMM

  cvt_f32_bf16<<<12288, 256, 0, stream>>>(X, Xb, SEQ * HDIM / 8);
  cvt_f32_bf16<<<4608, 256, 0, stream>>>(Wq, Wqkvb, HDIM * HDIM / 8);
  cvt_f32_bf16<<<4608, 256, 0, stream>>>(Wk, Wqkvb + (size_t)HDIM * HDIM, HDIM * HDIM / 8);
  cvt_f32_bf16<<<4608, 256, 0, stream>>>(Wv, Wqkvb + (size_t)2 * HDIM * HDIM, HDIM * HDIM / 8);
  cvt_f32_bf16<<<4608, 256, 0, stream>>>(Wo, Wob, HDIM * HDIM / 8);
  biascat<<<36, 256, 0, stream>>>(bq, bk, bv, biasQ);

  gemm256<true><<<dim3((SEQ / 256) * (QKVN / 256)), 512, 0, stream>>>(
      Xb, Wqkvb, biasQ, nullptr, QKV, Vt, QKVN, HDIM);

  attn_kernel<<<dim3(8, NHEAD, NWIN), 256, 0, stream>>>(QKV, Vt, ctxw);

  combine_kernel<<<12288, 256, 0, stream>>>(ctxw, ctx_avg);

  gemm256<false><<<dim3((SEQ / 256) * (HDIM / 256)), 512, 0, stream>>>(
      ctx_avg, Wob, bo, out, nullptr, nullptr, HDIM, HDIM);
}

// Round 13
// 837.533 us; speedup vs baseline: 1.4684x; 1.0166x over previous
//
#include <hip/hip_runtime.h>
#include <hip/hip_bf16.h>
#include <stdint.h>

// Problem constants
#define SEQ   8192
#define HDIM  3072
#define NWIN  19
#define WINL  512
#define STR   448
#define NHEAD 12
#define DHEAD 256
#define QKVN  9216
#define ATTN_SCALE 0.0625f

typedef unsigned short u16;
typedef __bf16 bf16x8 __attribute__((ext_vector_type(8)));
typedef float  f32x4  __attribute__((ext_vector_type(4)));
typedef unsigned short us8 __attribute__((ext_vector_type(8)));

__device__ __forceinline__ u16 f2b(float x) {
  return __builtin_bit_cast(u16, __float2bfloat16(x));
}
__device__ __forceinline__ float b2f(u16 u) {
  return __builtin_bit_cast(float, (unsigned int)(u) << 16);
}
__device__ __forceinline__ void gload_lds16(const void* g, void* l) {
  __builtin_amdgcn_global_load_lds(
      (const __attribute__((address_space(1))) void*)g,
      (__attribute__((address_space(3))) void*)l, 16, 0, 0);
}

// ---------------- fused elementwise prep: all cvts + biascat in ONE dispatch ----------------
// Block ranges (each exactly grid-aligned, no bounds checks needed):
//   [0,12288)      X  -> Xb      (8192*3072/8  = 3145728 groups = 12288*256)
//   [12288,16896)  Wq -> Wqkvb
//   [16896,21504)  Wk -> Wqkvb + 9437184
//   [21504,26112)  Wv -> Wqkvb + 18874368
//   [26112,30720)  Wo -> Wob    (3072*3072/8 = 1179648 = 4608*256 each)
//   [30720,30756)  biascat       (9216 = 36*256)
__device__ __forceinline__ void cvt8(const float* __restrict__ src,
                                     u16* __restrict__ dst, int i) {
  const float4* s4 = (const float4*)src;
  float4 a = s4[2 * i], b = s4[2 * i + 1];
  us8 o;
  o[0] = f2b(a.x); o[1] = f2b(a.y); o[2] = f2b(a.z); o[3] = f2b(a.w);
  o[4] = f2b(b.x); o[5] = f2b(b.y); o[6] = f2b(b.z); o[7] = f2b(b.w);
  *((us8*)dst + i) = o;
}

__global__ __launch_bounds__(256) void prep_kernel(
    const float* __restrict__ X,  const float* __restrict__ Wq,
    const float* __restrict__ Wk, const float* __restrict__ Wv,
    const float* __restrict__ Wo, const float* __restrict__ bq,
    const float* __restrict__ bk, const float* __restrict__ bv,
    u16* __restrict__ Xb, u16* __restrict__ Wqkvb, u16* __restrict__ Wob,
    float* __restrict__ biasQ) {
  const int b = blockIdx.x, t = threadIdx.x;
  if (b < 12288) {
    cvt8(X, Xb, b * 256 + t);
  } else if (b < 16896) {
    cvt8(Wq, Wqkvb, (b - 12288) * 256 + t);
  } else if (b < 21504) {
    cvt8(Wk, Wqkvb + (size_t)HDIM * HDIM, (b - 16896) * 256 + t);
  } else if (b < 26112) {
    cvt8(Wv, Wqkvb + (size_t)2 * HDIM * HDIM, (b - 21504) * 256 + t);
  } else if (b < 30720) {
    cvt8(Wo, Wob, (b - 26112) * 256 + t);
  } else {
    const int i = (b - 30720) * 256 + t;  // < 9216 exactly
    biasQ[i] = (i < HDIM) ? bq[i] : ((i < 2 * HDIM) ? bk[i - HDIM] : bv[i - 2 * HDIM]);
  }
}

// ---------------- 256x256 8-phase GEMM (R4-exact): C = A * B^T (+bias) ----------------
// A[M][K] bf16 row-major, B[N][K] bf16 row-major. K-tile BK=64.
// 8 waves (2Mx4N). INTERLEAVED ownership (correctness-critical):
//   C rows  mi*32 + wm*16 + {0..15}, mi=0..7  (mi0-3 in A-lo half, mi4-7 A-hi)
//   C cols  ni*64 + wn*16 + {0..15}, ni=0..3  (ni0-1 in B-lo half, ni2-3 B-hi)
// => P0 touches ONLY lo halves for every wave; half-readiness matches vmcnt ledger.
// LDS: [2 dbuf][2 half][128][64] per operand = 128 KiB. 16B-chunk swizzle:
// phys_chunk = logical ^ (row&7), both sides.
// If BF16OUT and vtOut != nullptr, columns c >= 2*HDIM also write the
// transposed V panel: Vt[(c-6144)][r0..r0+3] (one 8B store per (mi,ni)).
template <bool BF16OUT>
__global__ __launch_bounds__(512, 2) void gemm256(const u16* __restrict__ A,
                                                  const u16* __restrict__ B,
                                                  const float* __restrict__ bias,
                                                  float* __restrict__ outF,
                                                  u16* __restrict__ outB,
                                                  u16* __restrict__ vtOut,
                                                  int N, int K) {
  __shared__ __align__(16) u16 As[2][2][128][64];
  __shared__ __align__(16) u16 Bs[2][2][128][64];
  const int tid = threadIdx.x;
  const int w = tid >> 6, l = tid & 63;
  const int wm = w >> 2, wn = w & 3;
  const int fr = l & 15, g = l >> 4;
  // XCD-band mapping (hardware round-robin bid->XCD = bid%8); nbm = 32 = 8x4.
  const int xcd = blockIdx.x & 7, loc = blockIdx.x >> 3;
  const int bn = loc >> 2, bm = xcd * 4 + (loc & 3);

  // Staging: thread t writes half bytes t*16 and 8192+t*16
  //  -> rows t>>3 and 64+(t>>3), phys chunk t&7; source chunk inverse-swizzled.
  const int srow = tid >> 3;
  const int lc = (tid & 7) ^ ((tid >> 3) & 7);
  const u16* sA0 = A + (size_t)(bm * 256 + srow) * K + lc * 8;
  const u16* sA1 = sA0 + (size_t)64 * K;
  const u16* sB0 = B + (size_t)(bn * 256 + srow) * K + lc * 8;
  const u16* sB1 = sB0 + (size_t)64 * K;
  const size_t hiK = (size_t)128 * K;
  const int t16 = tid * 16;
  char* Aw = (char*)As;
  char* Bw = (char*)Bs;

  // Fragment read offsets (bytes within a [128][64] half):
  //  A row = mi*32 + wm*16 + fr ; B row = (ni&1)*64 + wn*16 + fr
  //  chunk = (kk*4+g) ^ (row&7); row&7 == fr&7 for all fragments.
  int rbA[4], rbB[2], ck[2];
#pragma unroll
  for (int i = 0; i < 4; ++i) rbA[i] = (i * 32 + wm * 16 + fr) * 128;
  rbB[0] = (wn * 16 + fr) * 128;
  rbB[1] = (64 + wn * 16 + fr) * 128;
  ck[0] = ((g) ^ (fr & 7)) * 16;
  ck[1] = ((4 + g) ^ (fr & 7)) * 16;

  f32x4 acc[8][4];
#pragma unroll
  for (int i = 0; i < 8; ++i)
#pragma unroll
    for (int j = 0; j < 4; ++j) acc[i][j] = (f32x4){0.f, 0.f, 0.f, 0.f};

  // prologue: stage tile0 (Alo,Blo,Bhi,Ahi) into parity 0
  gload_lds16(sA0, Aw + t16); gload_lds16(sA1, Aw + 8192 + t16);
  gload_lds16(sB0, Bw + t16); gload_lds16(sB1, Bw + 8192 + t16);
  gload_lds16(sB0 + hiK, Bw + 16384 + t16); gload_lds16(sB1 + hiK, Bw + 16384 + 8192 + t16);
  gload_lds16(sA0 + hiK, Aw + 16384 + t16); gload_lds16(sA1 + hiK, Aw + 16384 + 8192 + t16);
  sA0 += 64; sA1 += 64; sB0 += 64; sB1 += 64;  // -> tile 1
  asm volatile("s_waitcnt vmcnt(4)" ::: "memory");
  __builtin_amdgcn_s_barrier();
  __builtin_amdgcn_sched_barrier(0);

  const int NT = K >> 6;
  for (int T = 0; T < NT; ++T) {
    const int cur = T & 1, pp = (T + 1) & 1;
    const bool ds = (T + 1 < NT);
    const bool last = (T == NT - 1);
    const char* ah = (const char*)As + cur * 32768;
    const char* bh = (const char*)Bs + cur * 32768;
    char* apw = Aw + pp * 32768;
    char* bpw = Bw + pp * 32768;
    bf16x8 af[4][2], bf[4][2];

    // ---------------- P0 ----------------
#pragma unroll
    for (int mi = 0; mi < 4; ++mi)
#pragma unroll
      for (int kk = 0; kk < 2; ++kk)
        af[mi][kk] = *(const bf16x8*)(ah + rbA[mi] + ck[kk]);
#pragma unroll
    for (int ni = 0; ni < 2; ++ni)
#pragma unroll
      for (int kk = 0; kk < 2; ++kk)
        bf[ni][kk] = *(const bf16x8*)(bh + rbB[ni] + ck[kk]);
    if (ds) { gload_lds16(sA0, apw + t16); gload_lds16(sA1, apw + 8192 + t16); }
    __builtin_amdgcn_s_barrier();
    asm volatile("s_waitcnt lgkmcnt(0)" ::: "memory");
    __builtin_amdgcn_sched_barrier(0);
    __builtin_amdgcn_s_setprio(1);
#pragma unroll
    for (int kk = 0; kk < 2; ++kk)
#pragma unroll
      for (int mi = 0; mi < 4; ++mi)
#pragma unroll
        for (int ni = 0; ni < 2; ++ni)
          acc[mi][ni] = __builtin_amdgcn_mfma_f32_16x16x32_bf16(af[mi][kk], bf[ni][kk], acc[mi][ni], 0, 0, 0);
    __builtin_amdgcn_s_setprio(0);
    if (last) asm volatile("s_waitcnt vmcnt(2)" ::: "memory");
    else      asm volatile("s_waitcnt vmcnt(4)" ::: "memory");
    __builtin_amdgcn_s_barrier();

    // ---------------- P1 ----------------
#pragma unroll
    for (int ni = 2; ni < 4; ++ni)
#pragma unroll
      for (int kk = 0; kk < 2; ++kk)
        bf[ni][kk] = *(const bf16x8*)(bh + 16384 + rbB[ni - 2] + ck[kk]);
    if (ds) { gload_lds16(sB0, bpw + t16); gload_lds16(sB1, bpw + 8192 + t16); }
    __builtin_amdgcn_s_barrier();
    asm volatile("s_waitcnt lgkmcnt(0)" ::: "memory");
    __builtin_amdgcn_sched_barrier(0);
    __builtin_amdgcn_s_setprio(1);
#pragma unroll
    for (int kk = 0; kk < 2; ++kk)
#pragma unroll
      for (int mi = 0; mi < 4; ++mi)
#pragma unroll
        for (int ni = 2; ni < 4; ++ni)
          acc[mi][ni] = __builtin_amdgcn_mfma_f32_16x16x32_bf16(af[mi][kk], bf[ni][kk], acc[mi][ni], 0, 0, 0);
    __builtin_amdgcn_s_setprio(0);
    if (last) asm volatile("s_waitcnt vmcnt(0)" ::: "memory");
    else      asm volatile("s_waitcnt vmcnt(4)" ::: "memory");
    __builtin_amdgcn_s_barrier();

    // ---------------- P2 ----------------
#pragma unroll
    for (int mi = 0; mi < 4; ++mi)
#pragma unroll
      for (int kk = 0; kk < 2; ++kk)
        af[mi][kk] = *(const bf16x8*)(ah + 16384 + rbA[mi] + ck[kk]);
    if (ds) { gload_lds16(sB0 + hiK, bpw + 16384 + t16); gload_lds16(sB1 + hiK, bpw + 16384 + 8192 + t16); }
    __builtin_amdgcn_s_barrier();
    asm volatile("s_waitcnt lgkmcnt(0)" ::: "memory");
    __builtin_amdgcn_sched_barrier(0);
    __builtin_amdgcn_s_setprio(1);
#pragma unroll
    for (int kk = 0; kk < 2; ++kk)
#pragma unroll
      for (int mi = 0; mi < 4; ++mi)
#pragma unroll
        for (int ni = 0; ni < 2; ++ni)
          acc[mi + 4][ni] = __builtin_amdgcn_mfma_f32_16x16x32_bf16(af[mi][kk], bf[ni][kk], acc[mi + 4][ni], 0, 0, 0);
    __builtin_amdgcn_s_setprio(0);
    __builtin_amdgcn_s_barrier();

    // ---------------- P3 ----------------
    if (ds) { gload_lds16(sA0 + hiK, apw + 16384 + t16); gload_lds16(sA1 + hiK, apw + 16384 + 8192 + t16); }
    __builtin_amdgcn_s_barrier();
    __builtin_amdgcn_s_setprio(1);
#pragma unroll
    for (int kk = 0; kk < 2; ++kk)
#pragma unroll
      for (int mi = 0; mi < 4; ++mi)
#pragma unroll
        for (int ni = 2; ni < 4; ++ni)
          acc[mi + 4][ni] = __builtin_amdgcn_mfma_f32_16x16x32_bf16(af[mi][kk], bf[ni][kk], acc[mi + 4][ni], 0, 0, 0);
    __builtin_amdgcn_s_setprio(0);
    if (!last) asm volatile("s_waitcnt vmcnt(4)" ::: "memory");
    __builtin_amdgcn_s_barrier();
    if (ds) { sA0 += 64; sA1 += 64; sB0 += 64; sB1 += 64; }
    __builtin_amdgcn_sched_barrier(0);
  }

  // epilogue (+ optional fused V-transpose write)
#pragma unroll
  for (int ni = 0; ni < 4; ++ni) {
    const int c = bn * 256 + ni * 64 + wn * 16 + fr;
    const float bvv = bias ? bias[c] : 0.0f;
    const bool wv = BF16OUT && (vtOut != nullptr) && (c >= 2 * HDIM);
#pragma unroll
    for (int mi = 0; mi < 8; ++mi) {
      const int r0 = bm * 256 + mi * 32 + wm * 16 + g * 4;
      u16 t4[4];
#pragma unroll
      for (int jj = 0; jj < 4; ++jj) {
        float v = acc[mi][ni][jj] + bvv;
        if (BF16OUT) { u16 b_ = f2b(v); outB[(size_t)(r0 + jj) * N + c] = b_; t4[jj] = b_; }
        else         outF[(size_t)(r0 + jj) * N + c] = v;
      }
      if (wv) *(uint2*)(vtOut + (size_t)(c - 2 * HDIM) * SEQ + r0) = *(const uint2*)t4;
    }
  }
}

// ---------------- windowed flash attention (R1-exact + wave-private-Ps fence) ----------------
// grid (8 qb, 12 h, 19 win), 4 waves. Each wave: 16 q-rows, online softmax over
// 8 chunks of 64 kv. LDS: Ks 32KB + Vts 32KB + Ps 8KB = 72KB -> 2 blocks/CU.
// 2 barriers/kt: post-stage (__syncthreads drains vmcnt) and end-of-kt.
// Ps is wave-private -> same-wave ds_write->ds_read ordered by lgkmcnt(0)
// + sched_barrier(0) (rule #18; validated in R9/R11/R12 refchecks).
__global__ __launch_bounds__(256, 2) void attn_kernel(const u16* __restrict__ QKV,
                                                      const u16* __restrict__ Vt,
                                                      u16* __restrict__ ctxw) {
  __shared__ __align__(16) u16 Ks[64 * 256];   // [kv][d], chunk-swizzled (XOR row&31)
  __shared__ __align__(16) u16 Vts[256 * 64];  // [d][kv], chunk-swizzled (XOR row&7)
  __shared__ __align__(16) u16 Ps[4][16 * 64]; // per-wave P scratch, XOR (q&7)<<4
  const int qb = blockIdx.x, h = blockIdx.y, n = blockIdx.z;
  const int tid = threadIdx.x, w = tid >> 6, l = tid & 63;
  const int g = l >> 4, fr = l & 15;
  const int s0 = n * STR;

  // Q fragments (16 rows per wave) straight from global
  bf16x8 qf[8];
  {
    int sq = s0 + qb * 64 + w * 16 + fr;
    if (sq > SEQ - 1) sq = SEQ - 1;
    const u16* qbase = QKV + (size_t)sq * QKVN + h * DHEAD + g * 8;
#pragma unroll
    for (int dc = 0; dc < 8; ++dc) qf[dc] = *(const bf16x8*)(qbase + dc * 32);
  }
  f32x4 ctx[16];
#pragma unroll
  for (int dn = 0; dn < 16; ++dn) ctx[dn] = (f32x4){0.f, 0.f, 0.f, 0.f};
  float mrow[4] = {-3e38f, -3e38f, -3e38f, -3e38f};
  float lrow[4] = {0.f, 0.f, 0.f, 0.f};

  const int kr_in = l >> 5;  // K staging: row within 2-row chunk
  const int kcp = l & 31;    // K staging: physical 16B chunk in row
  const int vr_in = l >> 3;  // V staging: row within 8-row chunk
  const int vcp = l & 7;
  char* pw = (char*)&Ps[w][0];

  for (int kt = 0; kt < 8; ++kt) {
    const int sb = s0 + kt * 64;
    // ---- stage K[64][256] and Vt-slice[256][64], source pre-swizzled ----
#pragma unroll
    for (int i = 0; i < 8; ++i) {
      const int c = i * 4 + w;  // 1KB chunk id, 0..31
      {
        const int krow = c * 2 + kr_in;
        const int cl = kcp ^ (krow & 31);
        int sk = sb + krow;
        if (sk > SEQ - 1) sk = SEQ - 1;
        gload_lds16(QKV + (size_t)sk * QKVN + HDIM + h * DHEAD + cl * 8, (char*)Ks + c * 1024);
      }
      {
        const int d = c * 8 + vr_in;
        const int cl = vcp ^ (d & 7);
        int sv = sb + cl * 8;
        if (sv > SEQ - 8) sv = SEQ - 8;
        gload_lds16(Vt + (size_t)(h * DHEAD + d) * SEQ + sv, (char*)Vts + c * 1024);
      }
    }
    __syncthreads();

    // ---- S = Q K^T (rows q=(g*4+r), cols kv=kn*16+fr) ----
    f32x4 sacc[4];
#pragma unroll
    for (int kn = 0; kn < 4; ++kn) sacc[kn] = (f32x4){0.f, 0.f, 0.f, 0.f};
#pragma unroll
    for (int kn = 0; kn < 4; ++kn) {
      const int krow = kn * 16 + fr;
      const char* krp = (const char*)Ks + krow * 512;
      const int rx = krow & 31;
#pragma unroll
      for (int dc = 0; dc < 8; ++dc) {
        bf16x8 kf = *(const bf16x8*)(krp + (((dc * 4 + g) ^ rx) << 4));
        sacc[kn] = __builtin_amdgcn_mfma_f32_16x16x32_bf16(qf[dc], kf, sacc[kn], 0, 0, 0);
      }
    }
    // ---- scale + validity mask + online softmax ----
    float mt[4];
#pragma unroll
    for (int kn = 0; kn < 4; ++kn) {
      const bool valid = (sb + kn * 16 + fr) < SEQ;
#pragma unroll
      for (int r = 0; r < 4; ++r) {
        float v = valid ? sacc[kn][r] * ATTN_SCALE : -1e9f;
        sacc[kn][r] = v;
        mt[r] = (kn == 0) ? v : fmaxf(mt[r], v);
      }
    }
#pragma unroll
    for (int r = 0; r < 4; ++r) {
#pragma unroll
      for (int off = 1; off < 16; off <<= 1)
        mt[r] = fmaxf(mt[r], __shfl_xor(mt[r], off, 64));
    }
    float corr[4];
#pragma unroll
    for (int r = 0; r < 4; ++r) {
      float mnew = fmaxf(mrow[r], mt[r]);
      corr[r] = __expf(mrow[r] - mnew);
      mrow[r] = mnew;
    }
    float psum[4] = {0.f, 0.f, 0.f, 0.f};
#pragma unroll
    for (int kn = 0; kn < 4; ++kn) {
#pragma unroll
      for (int r = 0; r < 4; ++r) {
        float p = __expf(sacc[kn][r] - mrow[r]);
        psum[r] += p;
        const int q = g * 4 + r;
        *(u16*)(pw + q * 128 + ((2 * (kn * 16 + fr)) ^ ((q & 7) << 4))) = f2b(p);
      }
    }
#pragma unroll
    for (int r = 0; r < 4; ++r) {
#pragma unroll
      for (int off = 1; off < 16; off <<= 1)
        psum[r] += __shfl_xor(psum[r], off, 64);
      lrow[r] = lrow[r] * corr[r] + psum[r];
    }
#pragma unroll
    for (int dn = 0; dn < 16; ++dn)
#pragma unroll
      for (int r = 0; r < 4; ++r) ctx[dn][r] *= corr[r];
    // same-wave ds_write -> ds_read ordering for wave-private Ps (rule #18)
    asm volatile("s_waitcnt lgkmcnt(0)" ::: "memory");
    __builtin_amdgcn_sched_barrier(0);

    // ---- ctx += P * V (via Vt rows as B^T) ----
    bf16x8 pf[2];
#pragma unroll
    for (int kc = 0; kc < 2; ++kc)
      pf[kc] = *(const bf16x8*)(pw + fr * 128 + ((kc * 64 + g * 16) ^ ((fr & 7) << 4)));
#pragma unroll
    for (int dn = 0; dn < 16; ++dn) {
      const int d = dn * 16 + fr;
      const char* vrp = (const char*)Vts + d * 128;
      const int dx = d & 7;
#pragma unroll
      for (int kc = 0; kc < 2; ++kc) {
        bf16x8 vf = *(const bf16x8*)(vrp + (((kc * 4 + g) ^ dx) << 4));
        ctx[dn] = __builtin_amdgcn_mfma_f32_16x16x32_bf16(pf[kc], vf, ctx[dn], 0, 0, 0);
      }
    }
    __syncthreads();  // all waves done with Ks/Vts before next stage
  }
  // ---- epilogue: normalize and store ctx ----
  float inv[4];
#pragma unroll
  for (int r = 0; r < 4; ++r) inv[r] = 1.0f / lrow[r];
  const int qrow0 = qb * 64 + w * 16 + g * 4;
#pragma unroll
  for (int dn = 0; dn < 16; ++dn) {
#pragma unroll
    for (int r = 0; r < 4; ++r) {
      ctxw[(size_t)(n * WINL + qrow0 + r) * HDIM + h * DHEAD + dn * 16 + fr] =
          f2b(ctx[dn][r] * inv[r]);
    }
  }
}

// ---------------- overlap-average combine: ctx_avg[8192][3072] ----------------
__global__ __launch_bounds__(256) void combine_kernel(const u16* __restrict__ ctxw,
                                                      u16* __restrict__ ctx_avg) {
  int idx = blockIdx.x * 256 + threadIdx.x;
  if (idx >= SEQ * (HDIM / 8)) return;
  const int s = idx / (HDIM / 8);
  const int cc = (idx % (HDIM / 8)) * 8;
  const int w1 = s / STR;          // <= 18
  const int off1 = s - w1 * STR;   // 0..447
  us8 a = *(const us8*)(ctxw + (size_t)(w1 * WINL + off1) * HDIM + cc);
  if (w1 >= 1 && off1 < (WINL - STR)) {
    us8 b = *(const us8*)(ctxw + (size_t)((w1 - 1) * WINL + off1 + STR) * HDIM + cc);
#pragma unroll
    for (int j = 0; j < 8; ++j) a[j] = f2b(0.5f * (b2f(a[j]) + b2f(b[j])));
  }
  *(us8*)(ctx_avg + (size_t)s * HDIM + cc) = a;
}

__global__ void ws_marker(float* out, float v) { out[0] = v; }

// ---------------- launch ----------------
extern "C" void kernel_launch(void* const* d_in, const int* in_sizes, int n_in,
                              void* d_out, int out_size, void* d_ws, size_t ws_size,
                              hipStream_t stream) {
  const float* X  = (const float*)d_in[0];
  const float* Wq = (const float*)d_in[1];
  const float* bq = (const float*)d_in[2];
  const float* Wk = (const float*)d_in[3];
  const float* bk = (const float*)d_in[4];
  const float* Wv = (const float*)d_in[5];
  const float* bv = (const float*)d_in[6];
  const float* Wo = (const float*)d_in[7];
  const float* bo = (const float*)d_in[8];
  float* out = (float*)d_out;

  // workspace layout (bytes)
  const size_t OFF_XB   = 0;                          // 8192*3072*2   = 50331648
  const size_t OFF_WQKV = 50331648;                   // 9216*3072*2   = 56623104
  const size_t OFF_WO   = 106954752;                  // 3072*3072*2   = 18874368
  const size_t OFF_QKV  = 125829120;                  // 8192*9216*2   = 150994944
  const size_t OFF_VT   = 276824064;                  // 3072*8192*2   = 50331648
  const size_t OFF_BIAS = 327155712;                  // 9216*4        = 36864
  const size_t WS_NEED  = 327192576;
  if (ws_size < WS_NEED) {
    hipMemsetAsync(d_out, 0, (size_t)out_size * 4, stream);
    ws_marker<<<1, 1, 0, stream>>>(out, (float)(ws_size / 1048576));
    return;
  }
  char* ws = (char*)d_ws;
  u16* Xb      = (u16*)(ws + OFF_XB);
  u16* Wqkvb   = (u16*)(ws + OFF_WQKV);
  u16* Wob     = (u16*)(ws + OFF_WO);
  u16* QKV     = (u16*)(ws + OFF_QKV);
  u16* Vt      = (u16*)(ws + OFF_VT);
  float* biasQ = (float*)(ws + OFF_BIAS);
  u16* ctxw    = (u16*)d_out;  // 59.8MB scratch inside the 100.7MB output buffer
  u16* ctx_avg = Xb;           // alias: Xb dead after QKV GEMM

  prep_kernel<<<30756, 256, 0, stream>>>(X, Wq, Wk, Wv, Wo, bq, bk, bv,
                                         Xb, Wqkvb, Wob, biasQ);

  gemm256<true><<<dim3((SEQ / 256) * (QKVN / 256)), 512, 0, stream>>>(
      Xb, Wqkvb, biasQ, nullptr, QKV, Vt, QKVN, HDIM);

  attn_kernel<<<dim3(8, NHEAD, NWIN), 256, 0, stream>>>(QKV, Vt, ctxw);

  combine_kernel<<<12288, 256, 0, stream>>>(ctxw, ctx_avg);

  gemm256<false><<<dim3((SEQ / 256) * (HDIM / 256)), 512, 0, stream>>>(
      ctx_avg, Wob, bo, out, nullptr, nullptr, HDIM, HDIM);
}